// Round 4
// baseline (1749.011 us; speedup 1.0000x reference)
//
#include <hip/hip_runtime.h>
#include <hip/hip_bf16.h>

// GCN 2-layer surrogate. Bucketed edge partition + LDS-resident aggregation.
//   bucket = dst >> 8 (391 buckets x 256 nodes)
//   hist:  bucket histogram; bscan: bucket starts
//   part:  bin edges by bucket, emit packed int: src | (dst&255)<<20  (12.8 MB)
//   degs:  per-bucket node degree -> dinv = rsqrt(deg+1)
//   gemm1: hs_bf16 = bf16( dinv[r] * (x @ W1) )        (12.8 MB table)
//   agg1:  per half-bucket block: LDS f32 acc[128x64]; shfl-broadcast edge loop,
//          bf16 row gather + ds_add_f32; fused epilogue relu + (64->2) + pre-scale
//   agg2:  per bucket: LDS acc[256x2]; thread-per-edge gather of hs2; fused epilogue

#define N_NODES 100000
#define IN_DIM 128
#define HID_DIM 64
#define OUT_DIM 2
#define NB 391          // ceil(100000/256)
#define CHUNK 4096

__device__ __forceinline__ unsigned short f2bf(float x) {
    unsigned int u = __float_as_uint(x);
    unsigned int r = (u + 0x7FFFu + ((u >> 16) & 1u)) >> 16;   // RNE
    return (unsigned short)r;
}
__device__ __forceinline__ float bf2f(unsigned short h) {
    return __uint_as_float(((unsigned int)h) << 16);
}

// ---------------- A1: bucket histogram ----------------
__global__ __launch_bounds__(256) void hist_kernel(const int* __restrict__ dst,
                                                   int* __restrict__ gHist, int E) {
    __shared__ int h[NB];
    for (int i = threadIdx.x; i < NB; i += 256) h[i] = 0;
    __syncthreads();
    for (int e = blockIdx.x * 256 + threadIdx.x; e < E; e += gridDim.x * 256)
        atomicAdd(&h[dst[e] >> 8], 1);
    __syncthreads();
    for (int i = threadIdx.x; i < NB; i += 256)
        if (h[i]) atomicAdd(&gHist[i], h[i]);
}

// ---------------- B: scan bucket counts ----------------
__global__ __launch_bounds__(512) void bscan_kernel(const int* __restrict__ gHist,
                                                    int* __restrict__ bucketStart,
                                                    int* __restrict__ gCursor) {
    __shared__ int s[512];
    int t = threadIdx.x;
    int v = (t < NB) ? gHist[t] : 0;
    s[t] = v;
    __syncthreads();
#pragma unroll
    for (int off = 1; off < 512; off <<= 1) {
        int u = (t >= off) ? s[t - off] : 0;
        __syncthreads();
        s[t] += u;
        __syncthreads();
    }
    if (t < NB) {
        int st = s[t] - v;
        bucketStart[t] = st;
        gCursor[t] = st;
    }
}

// ---------------- A2: partition edges into bucket-ordered packed ints ----------------
__global__ __launch_bounds__(512) void part_kernel(const int* __restrict__ ei,
                                                   int* __restrict__ gCursor,
                                                   int* __restrict__ part, int E) {
    __shared__ int hist[512], lrow[512], gbase[512], lcur[512];
    __shared__ int lpk[CHUNK];
    __shared__ short lbkt[CHUNK];
    const int t = threadIdx.x;
    const int base = blockIdx.x * CHUNK;
    const int cntC = min(CHUNK, E - base);

    hist[t] = 0;
    __syncthreads();

    int s[8], d[8];
#pragma unroll
    for (int i = 0; i < 8; ++i) {
        int e = base + t + i * 512;
        if (e < E) {
            s[i] = ei[e];
            d[i] = ei[E + e];
            atomicAdd(&hist[d[i] >> 8], 1);
        }
    }
    __syncthreads();

    int v = hist[t];
    lrow[t] = v;
    __syncthreads();
#pragma unroll
    for (int off = 1; off < 512; off <<= 1) {
        int u = (t >= off) ? lrow[t - off] : 0;
        __syncthreads();
        lrow[t] += u;
        __syncthreads();
    }
    int excl = lrow[t] - v;
    if (t < NB && v > 0) gbase[t] = atomicAdd(&gCursor[t], v);
    lcur[t] = excl;
    lrow[t] = excl;                    // keep exclusive offsets for write-out
    __syncthreads();

#pragma unroll
    for (int i = 0; i < 8; ++i) {
        int e = base + t + i * 512;
        if (e < E) {
            int b = d[i] >> 8;
            int pos = atomicAdd(&lcur[b], 1);
            lpk[pos] = s[i] | ((d[i] & 255) << 20);
            lbkt[pos] = (short)b;
        }
    }
    __syncthreads();

    for (int i = t; i < cntC; i += 512) {
        int b = lbkt[i];
        part[gbase[b] + (i - lrow[b])] = lpk[i];
    }
}

// ---------------- degs: per-bucket degree -> dinv ----------------
__global__ __launch_bounds__(256) void degs_kernel(const int* __restrict__ part,
                                                   const int* __restrict__ gHist,
                                                   const int* __restrict__ bucketStart,
                                                   float* __restrict__ dinv, int n) {
    __shared__ int lcnt[256];
    const int b = blockIdx.x, t = threadIdx.x;
    const int start = bucketStart[b], count = gHist[b];
    lcnt[t] = 0;
    __syncthreads();
    for (int i = t; i < count; i += 256)
        atomicAdd(&lcnt[(part[start + i] >> 20) & 255], 1);
    __syncthreads();
    int node = (b << 8) + t;
    if (node < n) dinv[node] = rsqrtf((float)lcnt[t] + 1.0f);
}

// ---------------- GEMM1: hs_bf16 = bf16(dinv[r] * (x @ W1)) ----------------
__global__ __launch_bounds__(256) void gemm1_kernel(const float* __restrict__ x,
                                                    const float* __restrict__ W1,
                                                    const float* __restrict__ dinv,
                                                    unsigned short* __restrict__ hsb, int n) {
    __shared__ float sW[IN_DIM * HID_DIM];   // [k][c], 32 KB
    __shared__ float sX[64 * 132];           // [r][k], stride 132
    const int tid = threadIdx.x;
    const int rbase = blockIdx.x * 64;

#pragma unroll
    for (int i = 0; i < 32; ++i) sW[tid + i * 256] = W1[tid + i * 256];
#pragma unroll
    for (int j = 0; j < 32; ++j) {
        int idx = tid + j * 256;
        int r = idx >> 7, k = idx & 127;
        int gr = rbase + r;
        sX[r * 132 + k] = (gr < n) ? x[gr * IN_DIM + k] : 0.0f;
    }
    __syncthreads();

    const int tx = tid & 15, ty = tid >> 4;
    const int c0 = tx * 4, r0 = ty * 4;
    float acc[4][4] = {};

    for (int k0 = 0; k0 < IN_DIM; k0 += 4) {
        float as[4][4];
        float4 bv[4];
#pragma unroll
        for (int i = 0; i < 4; ++i) {
            float4 av = *(const float4*)&sX[(r0 + i) * 132 + k0];
            as[i][0] = av.x; as[i][1] = av.y; as[i][2] = av.z; as[i][3] = av.w;
        }
#pragma unroll
        for (int kk = 0; kk < 4; ++kk) bv[kk] = *(const float4*)&sW[(k0 + kk) * HID_DIM + c0];
#pragma unroll
        for (int i = 0; i < 4; ++i) {
#pragma unroll
            for (int kk = 0; kk < 4; ++kk) {
                acc[i][0] += as[i][kk] * bv[kk].x;
                acc[i][1] += as[i][kk] * bv[kk].y;
                acc[i][2] += as[i][kk] * bv[kk].z;
                acc[i][3] += as[i][kk] * bv[kk].w;
            }
        }
    }

#pragma unroll
    for (int i = 0; i < 4; ++i) {
        int r = rbase + r0 + i;
        if (r < n) {
            float di = dinv[r];
            ushort4 v;
            v.x = f2bf(acc[i][0] * di);
            v.y = f2bf(acc[i][1] * di);
            v.z = f2bf(acc[i][2] * di);
            v.w = f2bf(acc[i][3] * di);
            *(ushort4*)&hsb[r * HID_DIM + c0] = v;
        }
    }
}

// ---------------- agg1: half-bucket LDS accumulate + fused epilogue ----------------
__global__ __launch_bounds__(256) void agg1_kernel(const int* __restrict__ part,
                                                   const int* __restrict__ gHist,
                                                   const int* __restrict__ bucketStart,
                                                   const unsigned short* __restrict__ hsb,
                                                   const float* __restrict__ dinv,
                                                   const float* __restrict__ b1,
                                                   const float* __restrict__ W2,
                                                   float* __restrict__ hs2, int n) {
    __shared__ float acc[128 * HID_DIM];     // 32 KB
    const int bucket = blockIdx.x >> 1;
    const int half = blockIdx.x & 1;
    const int t = threadIdx.x;
    const int wave = t >> 6, lane = t & 63;
    const int start = bucketStart[bucket];
    const int end = start + gHist[bucket];

    for (int i = t; i < 128 * HID_DIM; i += 256) acc[i] = 0.0f;
    __syncthreads();

    for (int j0 = start + wave * 64; j0 < end; j0 += 256) {
        int m = min(64, end - j0);
        int pk = (lane < m) ? part[j0 + lane] : 0;
        for (int k = 0; k < m; ++k) {
            int p = __shfl(pk, k);
            int ld = (p >> 20) & 255;
            if ((ld >> 7) == half) {
                int s = p & 0xFFFFF;
                float v = bf2f(hsb[s * HID_DIM + lane]);
                atomicAdd(&acc[(ld & 127) * HID_DIM + lane], v);
            }
        }
    }
    __syncthreads();

    const int nodeBase = (bucket << 8) + (half << 7);
    const float bb = b1[lane];
    const float w20 = W2[lane * OUT_DIM + 0];
    const float w21 = W2[lane * OUT_DIM + 1];
    for (int i = wave; i < 128; i += 4) {
        int node = nodeBase + i;
        if (node >= n) break;
        float di = dinv[node];
        float a = acc[i * HID_DIM + lane] + bf2f(hsb[node * HID_DIM + lane]);
        float tt = fmaxf(fmaf(di, a, bb), 0.0f);
        float p0 = tt * w20, p1 = tt * w21;
#pragma unroll
        for (int off = 32; off > 0; off >>= 1) {
            p0 += __shfl_down(p0, off);
            p1 += __shfl_down(p1, off);
        }
        if (lane == 0) {
            hs2[node * OUT_DIM + 0] = di * p0;
            hs2[node * OUT_DIM + 1] = di * p1;
        }
    }
}

// ---------------- agg2: per-bucket LDS accumulate d=2 + fused epilogue ----------------
__global__ __launch_bounds__(256) void agg2_kernel(const int* __restrict__ part,
                                                   const int* __restrict__ gHist,
                                                   const int* __restrict__ bucketStart,
                                                   const float* __restrict__ hs2,
                                                   const float* __restrict__ dinv,
                                                   const float* __restrict__ b2,
                                                   float* __restrict__ out, int n) {
    __shared__ float a2[256 * OUT_DIM];      // 2 KB
    const int b = blockIdx.x, t = threadIdx.x;
    const int start = bucketStart[b];
    const int end = start + gHist[b];

    a2[t] = 0.0f;
    a2[t + 256] = 0.0f;
    __syncthreads();

    for (int i = start + t; i < end; i += 256) {
        int p = part[i];
        int s = p & 0xFFFFF;
        int ld = (p >> 20) & 255;
        float2 v = *(const float2*)&hs2[s * OUT_DIM];
        atomicAdd(&a2[ld * OUT_DIM + 0], v.x);
        atomicAdd(&a2[ld * OUT_DIM + 1], v.y);
    }
    __syncthreads();

    int node = (b << 8) + t;
    if (node < n) {
        float di = dinv[node];
        float2 self = *(const float2*)&hs2[node * OUT_DIM];
        out[node * OUT_DIM + 0] = di * (a2[t * OUT_DIM + 0] + self.x) + b2[0];
        out[node * OUT_DIM + 1] = di * (a2[t * OUT_DIM + 1] + self.y) + b2[1];
    }
}

extern "C" void kernel_launch(void* const* d_in, const int* in_sizes, int n_in,
                              void* d_out, int out_size, void* d_ws, size_t ws_size,
                              hipStream_t stream) {
    const float* x  = (const float*)d_in[0];
    const int*   ei = (const int*)d_in[1];     // [2][E], row 0 = src, row 1 = dst
    const float* W1 = (const float*)d_in[2];
    const float* b1 = (const float*)d_in[3];
    const float* W2 = (const float*)d_in[4];
    const float* b2 = (const float*)d_in[5];
    float* out = (float*)d_out;

    const int n = N_NODES;
    const int E = in_sizes[1] / 2;

    char* ws = (char*)d_ws;
    int*   gHist       = (int*)  (ws + 0);            // 1.6 KB
    int*   bucketStart = (int*)  (ws + (4u << 10));   // 1.6 KB
    int*   gCursor     = (int*)  (ws + (8u << 10));   // 1.6 KB
    float* dinv        = (float*)(ws + (1u << 20));   // 400 KB
    float* hs2         = (float*)(ws + (2u << 20));   // 800 KB
    int*   part        = (int*)  (ws + (3u << 20));   // 12.8 MB
    unsigned short* hsb = (unsigned short*)(ws + (16u << 20));  // 12.8 MB

    hipMemsetAsync(gHist, 0, NB * sizeof(int), stream);

    hist_kernel<<<1024, 256, 0, stream>>>(ei + E, gHist, E);
    bscan_kernel<<<1, 512, 0, stream>>>(gHist, bucketStart, gCursor);
    part_kernel<<<(E + CHUNK - 1) / CHUNK, 512, 0, stream>>>(ei, gCursor, part, E);
    degs_kernel<<<NB, 256, 0, stream>>>(part, gHist, bucketStart, dinv, n);

    gemm1_kernel<<<(n + 63) / 64, 256, 0, stream>>>(x, W1, dinv, hsb, n);
    agg1_kernel<<<NB * 2, 256, 0, stream>>>(part, gHist, bucketStart, hsb, dinv, b1, W2, hs2, n);
    agg2_kernel<<<NB, 256, 0, stream>>>(part, gHist, bucketStart, hs2, dinv, b2, out, n);
}

// Round 5
// 371.119 us; speedup vs baseline: 4.7128x; 4.7128x over previous
//
#include <hip/hip_runtime.h>
#include <hip/hip_bf16.h>

// GCN 2-layer surrogate. Bucketed counting-sort CSR + wave-per-node gather-reduce.
//   bucket = dst >> 8 (391 buckets x 256 nodes)
//   hist:  bucket histogram; bscan: bucket starts
//   part:  bin edges by bucket, emit packed int: src | (dst&255)<<20  (12.8 MB)
//   csr:   per bucket: LDS node-histogram -> cnt/dinv/rowptr + bucket-local
//          counting sort -> csr_src (src-only, 12.8 MB)
//   gemm1: hs_bf16 = bf16( dinv[r] * (x @ W1) )        (12.8 MB table)
//   agg1:  wave per node; 4 edges in flight (16 lanes x ushort4 per edge row);
//          register acc; fused relu + (64->2) + pre-scale epilogue
//   agg2:  wave per node, lane-parallel edges on d=2 table; fused epilogue

#define N_NODES 100000
#define IN_DIM 128
#define HID_DIM 64
#define OUT_DIM 2
#define NB 391          // ceil(100000/256)
#define CHUNK 4096

__device__ __forceinline__ unsigned short f2bf(float x) {
    unsigned int u = __float_as_uint(x);
    unsigned int r = (u + 0x7FFFu + ((u >> 16) & 1u)) >> 16;   // RNE
    return (unsigned short)r;
}
__device__ __forceinline__ float bf2f(unsigned short h) {
    return __uint_as_float(((unsigned int)h) << 16);
}

// ---------------- A1: bucket histogram ----------------
__global__ __launch_bounds__(256) void hist_kernel(const int* __restrict__ dst,
                                                   int* __restrict__ gHist, int E) {
    __shared__ int h[NB];
    for (int i = threadIdx.x; i < NB; i += 256) h[i] = 0;
    __syncthreads();
    for (int e = blockIdx.x * 256 + threadIdx.x; e < E; e += gridDim.x * 256)
        atomicAdd(&h[dst[e] >> 8], 1);
    __syncthreads();
    for (int i = threadIdx.x; i < NB; i += 256)
        if (h[i]) atomicAdd(&gHist[i], h[i]);
}

// ---------------- B: scan bucket counts ----------------
__global__ __launch_bounds__(512) void bscan_kernel(const int* __restrict__ gHist,
                                                    int* __restrict__ bucketStart,
                                                    int* __restrict__ gCursor) {
    __shared__ int s[512];
    int t = threadIdx.x;
    int v = (t < NB) ? gHist[t] : 0;
    s[t] = v;
    __syncthreads();
#pragma unroll
    for (int off = 1; off < 512; off <<= 1) {
        int u = (t >= off) ? s[t - off] : 0;
        __syncthreads();
        s[t] += u;
        __syncthreads();
    }
    if (t < NB) {
        int st = s[t] - v;
        bucketStart[t] = st;
        gCursor[t] = st;
    }
}

// ---------------- A2: partition edges into bucket-ordered packed ints ----------------
__global__ __launch_bounds__(512) void part_kernel(const int* __restrict__ ei,
                                                   int* __restrict__ gCursor,
                                                   int* __restrict__ part, int E) {
    __shared__ int hist[512], lrow[512], gbase[512], lcur[512];
    __shared__ int lpk[CHUNK];
    __shared__ short lbkt[CHUNK];
    const int t = threadIdx.x;
    const int base = blockIdx.x * CHUNK;
    const int cntC = min(CHUNK, E - base);

    hist[t] = 0;
    __syncthreads();

    int s[8], d[8];
#pragma unroll
    for (int i = 0; i < 8; ++i) {
        int e = base + t + i * 512;
        if (e < E) {
            s[i] = ei[e];
            d[i] = ei[E + e];
            atomicAdd(&hist[d[i] >> 8], 1);
        }
    }
    __syncthreads();

    int v = hist[t];
    lrow[t] = v;
    __syncthreads();
#pragma unroll
    for (int off = 1; off < 512; off <<= 1) {
        int u = (t >= off) ? lrow[t - off] : 0;
        __syncthreads();
        lrow[t] += u;
        __syncthreads();
    }
    int excl = lrow[t] - v;
    if (t < NB && v > 0) gbase[t] = atomicAdd(&gCursor[t], v);
    lcur[t] = excl;
    lrow[t] = excl;                    // keep exclusive offsets for write-out
    __syncthreads();

#pragma unroll
    for (int i = 0; i < 8; ++i) {
        int e = base + t + i * 512;
        if (e < E) {
            int b = d[i] >> 8;
            int pos = atomicAdd(&lcur[b], 1);
            lpk[pos] = s[i] | ((d[i] & 255) << 20);
            lbkt[pos] = (short)b;
        }
    }
    __syncthreads();

    for (int i = t; i < cntC; i += 512) {
        int b = lbkt[i];
        part[gbase[b] + (i - lrow[b])] = lpk[i];
    }
}

// ---------------- C: per-bucket CSR finalize (cnt/dinv/rowptr + src sort) ----------------
__global__ __launch_bounds__(256) void csr_kernel(const int* __restrict__ part,
                                                  const int* __restrict__ gHist,
                                                  const int* __restrict__ bucketStart,
                                                  int* __restrict__ cnt,
                                                  float* __restrict__ dinv,
                                                  int* __restrict__ rowptr,
                                                  int* __restrict__ csr_src, int n) {
    __shared__ int lcnt[256], lrow[256], lcur[256];
    const int b = blockIdx.x, t = threadIdx.x;
    const int start = bucketStart[b];
    const int count = gHist[b];

    lcnt[t] = 0;
    __syncthreads();
    for (int i = t; i < count; i += 256)
        atomicAdd(&lcnt[(part[start + i] >> 20) & 255], 1);
    __syncthreads();

    int v = lcnt[t];
    lrow[t] = v;
    __syncthreads();
#pragma unroll
    for (int off = 1; off < 256; off <<= 1) {
        int u = (t >= off) ? lrow[t - off] : 0;
        __syncthreads();
        lrow[t] += u;
        __syncthreads();
    }
    int excl = lrow[t] - v;
    int node = (b << 8) + t;
    if (node < n) {
        cnt[node] = v;
        dinv[node] = rsqrtf((float)v + 1.0f);
        rowptr[node] = start + excl;
    }
    lcur[t] = excl;
    __syncthreads();

    for (int i = t; i < count; i += 256) {
        int p = part[start + i];
        int pos = atomicAdd(&lcur[(p >> 20) & 255], 1);
        csr_src[start + pos] = p & 0xFFFFF;
    }
}

// ---------------- GEMM1: hs_bf16 = bf16(dinv[r] * (x @ W1)) ----------------
__global__ __launch_bounds__(256) void gemm1_kernel(const float* __restrict__ x,
                                                    const float* __restrict__ W1,
                                                    const float* __restrict__ dinv,
                                                    unsigned short* __restrict__ hsb, int n) {
    __shared__ float sW[IN_DIM * HID_DIM];   // [k][c], 32 KB
    __shared__ float sX[64 * 132];           // [r][k], stride 132
    const int tid = threadIdx.x;
    const int rbase = blockIdx.x * 64;

#pragma unroll
    for (int i = 0; i < 32; ++i) sW[tid + i * 256] = W1[tid + i * 256];
#pragma unroll
    for (int j = 0; j < 32; ++j) {
        int idx = tid + j * 256;
        int r = idx >> 7, k = idx & 127;
        int gr = rbase + r;
        sX[r * 132 + k] = (gr < n) ? x[gr * IN_DIM + k] : 0.0f;
    }
    __syncthreads();

    const int tx = tid & 15, ty = tid >> 4;
    const int c0 = tx * 4, r0 = ty * 4;
    float acc[4][4] = {};

    for (int k0 = 0; k0 < IN_DIM; k0 += 4) {
        float as[4][4];
        float4 bv[4];
#pragma unroll
        for (int i = 0; i < 4; ++i) {
            float4 av = *(const float4*)&sX[(r0 + i) * 132 + k0];
            as[i][0] = av.x; as[i][1] = av.y; as[i][2] = av.z; as[i][3] = av.w;
        }
#pragma unroll
        for (int kk = 0; kk < 4; ++kk) bv[kk] = *(const float4*)&sW[(k0 + kk) * HID_DIM + c0];
#pragma unroll
        for (int i = 0; i < 4; ++i) {
#pragma unroll
            for (int kk = 0; kk < 4; ++kk) {
                acc[i][0] += as[i][kk] * bv[kk].x;
                acc[i][1] += as[i][kk] * bv[kk].y;
                acc[i][2] += as[i][kk] * bv[kk].z;
                acc[i][3] += as[i][kk] * bv[kk].w;
            }
        }
    }

#pragma unroll
    for (int i = 0; i < 4; ++i) {
        int r = rbase + r0 + i;
        if (r < n) {
            float di = dinv[r];
            ushort4 v;
            v.x = f2bf(acc[i][0] * di);
            v.y = f2bf(acc[i][1] * di);
            v.z = f2bf(acc[i][2] * di);
            v.w = f2bf(acc[i][3] * di);
            *(ushort4*)&hsb[r * HID_DIM + c0] = v;
        }
    }
}

// ---------------- agg1: wave/node, 4 edges in flight, fused epilogue ----------------
// lane = g*16 + l: group g handles edges j = g, g+4, ...; lane loads ushort4 = dims l*4..l*4+3.
__global__ __launch_bounds__(256) void agg1_kernel(const int* __restrict__ rowptr,
                                                   const int* __restrict__ cnt,
                                                   const int* __restrict__ csr_src,
                                                   const unsigned short* __restrict__ hsb,
                                                   const float* __restrict__ dinv,
                                                   const float* __restrict__ b1,
                                                   const float* __restrict__ W2,
                                                   float* __restrict__ hs2, int n) {
    int node = blockIdx.x * 4 + (threadIdx.x >> 6);
    if (node >= n) return;
    int lane = threadIdx.x & 63;
    int g = lane >> 4;        // edge group
    int l = lane & 15;        // dim-quad
    int start = rowptr[node];
    int deg = cnt[node];

    float a0 = 0.0f, a1 = 0.0f, a2 = 0.0f, a3 = 0.0f;
    for (int j = g; j < deg; j += 4) {
        int s = csr_src[start + j];
        ushort4 v = *(const ushort4*)&hsb[s * HID_DIM + l * 4];
        a0 += bf2f(v.x);
        a1 += bf2f(v.y);
        a2 += bf2f(v.z);
        a3 += bf2f(v.w);
    }
    // combine the 4 edge-groups (dims identical across groups)
    a0 += __shfl_xor(a0, 16); a1 += __shfl_xor(a1, 16);
    a2 += __shfl_xor(a2, 16); a3 += __shfl_xor(a3, 16);
    a0 += __shfl_xor(a0, 32); a1 += __shfl_xor(a1, 32);
    a2 += __shfl_xor(a2, 32); a3 += __shfl_xor(a3, 32);

    // self-loop term
    ushort4 sv = *(const ushort4*)&hsb[node * HID_DIM + l * 4];
    a0 += bf2f(sv.x); a1 += bf2f(sv.y); a2 += bf2f(sv.z); a3 += bf2f(sv.w);

    float di = dinv[node];
    float4 bb = *(const float4*)&b1[l * 4];
    float t0 = fmaxf(fmaf(di, a0, bb.x), 0.0f);
    float t1 = fmaxf(fmaf(di, a1, bb.y), 0.0f);
    float t2 = fmaxf(fmaf(di, a2, bb.z), 0.0f);
    float t3 = fmaxf(fmaf(di, a3, bb.w), 0.0f);

    // W2 rows for dims l*4..l*4+3: [d][2] row-major
    float4 w01 = *(const float4*)&W2[l * 8];       // d0:{x,y} d1:{z,w}
    float4 w23 = *(const float4*)&W2[l * 8 + 4];   // d2:{x,y} d3:{z,w}
    float p0 = t0 * w01.x + t1 * w01.z + t2 * w23.x + t3 * w23.z;
    float p1 = t0 * w01.y + t1 * w01.w + t2 * w23.y + t3 * w23.w;
    // reduce over the 16 dim-quads (all 4 groups hold identical copies)
    p0 += __shfl_xor(p0, 1);  p1 += __shfl_xor(p1, 1);
    p0 += __shfl_xor(p0, 2);  p1 += __shfl_xor(p1, 2);
    p0 += __shfl_xor(p0, 4);  p1 += __shfl_xor(p1, 4);
    p0 += __shfl_xor(p0, 8);  p1 += __shfl_xor(p1, 8);

    if (lane == 0) {
        hs2[node * OUT_DIM + 0] = di * p0;
        hs2[node * OUT_DIM + 1] = di * p1;
    }
}

// ---------------- agg2: wave/node CSR gather d=2 + fused epilogue ----------------
__global__ __launch_bounds__(256) void agg2_kernel(const int* __restrict__ rowptr,
                                                   const int* __restrict__ cnt,
                                                   const int* __restrict__ csr_src,
                                                   const float* __restrict__ hs2,
                                                   const float* __restrict__ dinv,
                                                   const float* __restrict__ b2,
                                                   float* __restrict__ out, int n) {
    int node = blockIdx.x * 4 + (threadIdx.x >> 6);
    if (node >= n) return;
    int lane = threadIdx.x & 63;
    int start = rowptr[node];
    int deg = cnt[node];

    float a0 = 0.0f, a1 = 0.0f;
    for (int j = lane; j < deg; j += 64) {
        int s = csr_src[start + j];
        float2 v = *(const float2*)&hs2[s * OUT_DIM];
        a0 += v.x;
        a1 += v.y;
    }
#pragma unroll
    for (int off = 32; off > 0; off >>= 1) {
        a0 += __shfl_xor(a0, off);
        a1 += __shfl_xor(a1, off);
    }
    if (lane == 0) {
        float di = dinv[node];
        float2 self = *(const float2*)&hs2[node * OUT_DIM];
        out[node * OUT_DIM + 0] = di * (a0 + self.x) + b2[0];
        out[node * OUT_DIM + 1] = di * (a1 + self.y) + b2[1];
    }
}

extern "C" void kernel_launch(void* const* d_in, const int* in_sizes, int n_in,
                              void* d_out, int out_size, void* d_ws, size_t ws_size,
                              hipStream_t stream) {
    const float* x  = (const float*)d_in[0];
    const int*   ei = (const int*)d_in[1];     // [2][E], row 0 = src, row 1 = dst
    const float* W1 = (const float*)d_in[2];
    const float* b1 = (const float*)d_in[3];
    const float* W2 = (const float*)d_in[4];
    const float* b2 = (const float*)d_in[5];
    float* out = (float*)d_out;

    const int n = N_NODES;
    const int E = in_sizes[1] / 2;

    char* ws = (char*)d_ws;
    int*   gHist       = (int*)  (ws + 0);            // 1.6 KB
    int*   bucketStart = (int*)  (ws + (4u << 10));   // 1.6 KB
    int*   gCursor     = (int*)  (ws + (8u << 10));   // 1.6 KB
    int*   cnt         = (int*)  (ws + (1u << 20));   // 400 KB
    float* dinv        = (float*)(ws + (2u << 20));   // 400 KB
    int*   rowptr      = (int*)  (ws + (3u << 20));   // 400 KB
    float* hs2         = (float*)(ws + (4u << 20));   // 800 KB
    int*   part        = (int*)  (ws + (5u << 20));   // 12.8 MB
    int*   csr_src     = (int*)  (ws + (18u << 20));  // 12.8 MB
    unsigned short* hsb = (unsigned short*)(ws + (31u << 20));  // 12.8 MB

    hipMemsetAsync(gHist, 0, NB * sizeof(int), stream);

    hist_kernel<<<1024, 256, 0, stream>>>(ei + E, gHist, E);
    bscan_kernel<<<1, 512, 0, stream>>>(gHist, bucketStart, gCursor);
    part_kernel<<<(E + CHUNK - 1) / CHUNK, 512, 0, stream>>>(ei, gCursor, part, E);
    csr_kernel<<<NB, 256, 0, stream>>>(part, gHist, bucketStart, cnt, dinv, rowptr, csr_src, n);

    gemm1_kernel<<<(n + 63) / 64, 256, 0, stream>>>(x, W1, dinv, hsb, n);
    agg1_kernel<<<(n + 3) / 4, 256, 0, stream>>>(rowptr, cnt, csr_src, hsb, dinv, b1, W2, hs2, n);
    agg2_kernel<<<(n + 3) / 4, 256, 0, stream>>>(rowptr, cnt, csr_src, hs2, dinv, b2, out, n);
}

// Round 6
// 339.760 us; speedup vs baseline: 5.1478x; 1.0923x over previous
//
#include <hip/hip_runtime.h>
#include <hip/hip_bf16.h>

// GCN 2-layer surrogate. Bucketed counting-sort CSR + wave-per-node gather-reduce.
//   bucket = dst >> 8 (391 buckets x 256 nodes)
//   hist:  bucket histogram; bscan: bucket starts
//   part:  bin edges by bucket, emit packed int: src | (dst&255)<<20  (12.8 MB)
//   csr:   per bucket: LDS-staged edges, shfl-scan histogram -> cnt/dinv/rowptr,
//          bucket-local counting sort -> csr_src (12.8 MB)
//   gemm1: hs_bf16 = bf16( dinv[r] * (x @ W1) )        (12.8 MB table)
//   agg1:  wave per node; software-pipelined gather: 2 row-gathers + 2 index
//          prefetches in flight; fused relu + (64->2) + pre-scale epilogue
//   agg2:  wave per node, lane-parallel edges on d=2 table; fused epilogue

#define N_NODES 100000
#define IN_DIM 128
#define HID_DIM 64
#define OUT_DIM 2
#define NB 391          // ceil(100000/256)
#define CHUNK 4096

__device__ __forceinline__ unsigned short f2bf(float x) {
    unsigned int u = __float_as_uint(x);
    unsigned int r = (u + 0x7FFFu + ((u >> 16) & 1u)) >> 16;   // RNE
    return (unsigned short)r;
}
__device__ __forceinline__ float bf2f(unsigned short h) {
    return __uint_as_float(((unsigned int)h) << 16);
}
__device__ __forceinline__ int wave_incl_scan(int v, int laneid) {
#pragma unroll
    for (int off = 1; off < 64; off <<= 1) {
        int u = __shfl_up(v, off);
        if (laneid >= off) v += u;
    }
    return v;
}

// ---------------- A1: bucket histogram ----------------
__global__ __launch_bounds__(256) void hist_kernel(const int* __restrict__ dst,
                                                   int* __restrict__ gHist, int E) {
    __shared__ int h[NB];
    for (int i = threadIdx.x; i < NB; i += 256) h[i] = 0;
    __syncthreads();
    for (int e = blockIdx.x * 256 + threadIdx.x; e < E; e += gridDim.x * 256)
        atomicAdd(&h[dst[e] >> 8], 1);
    __syncthreads();
    for (int i = threadIdx.x; i < NB; i += 256)
        if (h[i]) atomicAdd(&gHist[i], h[i]);
}

// ---------------- B: scan bucket counts ----------------
__global__ __launch_bounds__(512) void bscan_kernel(const int* __restrict__ gHist,
                                                    int* __restrict__ bucketStart,
                                                    int* __restrict__ gCursor) {
    __shared__ int wsum[8], wofs[8];
    int t = threadIdx.x;
    int lane = t & 63, wv = t >> 6;
    int v = (t < NB) ? gHist[t] : 0;
    int inc = wave_incl_scan(v, lane);
    if (lane == 63) wsum[wv] = inc;
    __syncthreads();
    if (t < 64) {
        int w = (t < 8) ? wsum[t] : 0;
        int wi = wave_incl_scan(w, t);
        if (t < 8) wofs[t] = wi - w;
    }
    __syncthreads();
    if (t < NB) {
        int st = inc - v + wofs[wv];
        bucketStart[t] = st;
        gCursor[t] = st;
    }
}

// ---------------- A2: partition edges into bucket-ordered packed ints ----------------
__global__ __launch_bounds__(512) void part_kernel(const int* __restrict__ ei,
                                                   int* __restrict__ gCursor,
                                                   int* __restrict__ part, int E) {
    __shared__ int hist[512], lrow[512], gbase[512], lcur[512];
    __shared__ int lpk[CHUNK];
    __shared__ short lbkt[CHUNK];
    __shared__ int wsum[8], wofs[8];
    const int t = threadIdx.x;
    const int lane = t & 63, wv = t >> 6;
    const int base = blockIdx.x * CHUNK;
    const int cntC = min(CHUNK, E - base);

    hist[t] = 0;
    __syncthreads();

    int s[8], d[8];
#pragma unroll
    for (int i = 0; i < 8; ++i) {
        int e = base + t + i * 512;
        if (e < E) {
            s[i] = ei[e];
            d[i] = ei[E + e];
            atomicAdd(&hist[d[i] >> 8], 1);
        }
    }
    __syncthreads();

    int v = hist[t];
    int inc = wave_incl_scan(v, lane);
    if (lane == 63) wsum[wv] = inc;
    __syncthreads();
    if (t < 64) {
        int w = (t < 8) ? wsum[t] : 0;
        int wi = wave_incl_scan(w, t);
        if (t < 8) wofs[t] = wi - w;
    }
    __syncthreads();
    int excl = inc - v + wofs[wv];
    if (t < NB && v > 0) gbase[t] = atomicAdd(&gCursor[t], v);
    lcur[t] = excl;
    lrow[t] = excl;                    // exclusive offsets for write-out
    __syncthreads();

#pragma unroll
    for (int i = 0; i < 8; ++i) {
        int e = base + t + i * 512;
        if (e < E) {
            int b = d[i] >> 8;
            int pos = atomicAdd(&lcur[b], 1);
            lpk[pos] = s[i] | ((d[i] & 255) << 20);
            lbkt[pos] = (short)b;
        }
    }
    __syncthreads();

    for (int i = t; i < cntC; i += 512) {
        int b = lbkt[i];
        part[gbase[b] + (i - lrow[b])] = lpk[i];
    }
}

// ---------------- C: per-bucket CSR finalize (cnt/dinv/rowptr + src sort) ----------------
__global__ __launch_bounds__(256) void csr_kernel(const int* __restrict__ part,
                                                  const int* __restrict__ gHist,
                                                  const int* __restrict__ bucketStart,
                                                  int* __restrict__ cnt,
                                                  float* __restrict__ dinv,
                                                  int* __restrict__ rowptr,
                                                  int* __restrict__ csr_src, int n) {
    __shared__ int lcnt[256], lrow[256], lcur[256];
    __shared__ int epk[8192];          // 32 KB staging
    __shared__ int wsum[4], wofs[4];
    const int b = blockIdx.x, t = threadIdx.x;
    const int lane = t & 63, wv = t >> 6;
    const int start = bucketStart[b];
    const int count = gHist[b];
    const int cap = min(count, 8192);

    lcnt[t] = 0;
    __syncthreads();
    for (int i = t; i < count; i += 256) {
        int p = part[start + i];
        if (i < 8192) epk[i] = p;
        atomicAdd(&lcnt[(p >> 20) & 255], 1);
    }
    __syncthreads();

    int v = lcnt[t];
    int inc = wave_incl_scan(v, lane);
    if (lane == 63) wsum[wv] = inc;
    __syncthreads();
    if (t < 64) {
        int w = (t < 4) ? wsum[t] : 0;
        int wi = wave_incl_scan(w, t);
        if (t < 4) wofs[t] = wi - w;
    }
    __syncthreads();
    int excl = inc - v + wofs[wv];
    int node = (b << 8) + t;
    if (node < n) {
        cnt[node] = v;
        dinv[node] = rsqrtf((float)v + 1.0f);
        rowptr[node] = start + excl;
    }
    lcur[t] = excl;
    __syncthreads();

    for (int i = t; i < cap; i += 256) {
        int p = epk[i];
        int pos = atomicAdd(&lcur[(p >> 20) & 255], 1);
        csr_src[start + pos] = p & 0xFFFFF;
    }
    for (int i = 8192 + t; i < count; i += 256) {     // rare tail
        int p = part[start + i];
        int pos = atomicAdd(&lcur[(p >> 20) & 255], 1);
        csr_src[start + pos] = p & 0xFFFFF;
    }
}

// ---------------- GEMM1: hs_bf16 = bf16(dinv[r] * (x @ W1)) ----------------
__global__ __launch_bounds__(256) void gemm1_kernel(const float* __restrict__ x,
                                                    const float* __restrict__ W1,
                                                    const float* __restrict__ dinv,
                                                    unsigned short* __restrict__ hsb, int n) {
    __shared__ float sW[IN_DIM * HID_DIM];   // [k][c], 32 KB
    __shared__ float sX[64 * 132];           // [r][k], stride 132
    const int tid = threadIdx.x;
    const int rbase = blockIdx.x * 64;

#pragma unroll
    for (int i = 0; i < 32; ++i) sW[tid + i * 256] = W1[tid + i * 256];
#pragma unroll
    for (int j = 0; j < 32; ++j) {
        int idx = tid + j * 256;
        int r = idx >> 7, k = idx & 127;
        int gr = rbase + r;
        sX[r * 132 + k] = (gr < n) ? x[gr * IN_DIM + k] : 0.0f;
    }
    __syncthreads();

    const int tx = tid & 15, ty = tid >> 4;
    const int c0 = tx * 4, r0 = ty * 4;
    float acc[4][4] = {};

    for (int k0 = 0; k0 < IN_DIM; k0 += 4) {
        float as[4][4];
        float4 bv[4];
#pragma unroll
        for (int i = 0; i < 4; ++i) {
            float4 av = *(const float4*)&sX[(r0 + i) * 132 + k0];
            as[i][0] = av.x; as[i][1] = av.y; as[i][2] = av.z; as[i][3] = av.w;
        }
#pragma unroll
        for (int kk = 0; kk < 4; ++kk) bv[kk] = *(const float4*)&sW[(k0 + kk) * HID_DIM + c0];
#pragma unroll
        for (int i = 0; i < 4; ++i) {
#pragma unroll
            for (int kk = 0; kk < 4; ++kk) {
                acc[i][0] += as[i][kk] * bv[kk].x;
                acc[i][1] += as[i][kk] * bv[kk].y;
                acc[i][2] += as[i][kk] * bv[kk].z;
                acc[i][3] += as[i][kk] * bv[kk].w;
            }
        }
    }

#pragma unroll
    for (int i = 0; i < 4; ++i) {
        int r = rbase + r0 + i;
        if (r < n) {
            float di = dinv[r];
            ushort4 v;
            v.x = f2bf(acc[i][0] * di);
            v.y = f2bf(acc[i][1] * di);
            v.z = f2bf(acc[i][2] * di);
            v.w = f2bf(acc[i][3] * di);
            *(ushort4*)&hsb[r * HID_DIM + c0] = v;
        }
    }
}

// ---------------- agg1: wave/node, software-pipelined 8-edge steps ----------------
// lane = g*16 + l: group g handles edges j = g, g+4, ...; lane loads ushort4 = dims l*4..l*4+3.
// Two row-gathers + two index prefetches in flight per iteration.
__global__ __launch_bounds__(256) void agg1_kernel(const int* __restrict__ rowptr,
                                                   const int* __restrict__ cnt,
                                                   const int* __restrict__ csr_src,
                                                   const unsigned short* __restrict__ hsb,
                                                   const float* __restrict__ dinv,
                                                   const float* __restrict__ b1,
                                                   const float* __restrict__ W2,
                                                   float* __restrict__ hs2, int n) {
    int node = blockIdx.x * 4 + (threadIdx.x >> 6);
    if (node >= n) return;
    int lane = threadIdx.x & 63;
    int g = lane >> 4;        // edge group
    int l = lane & 15;        // dim-quad
    int start = rowptr[node];
    int deg = cnt[node];

    float a0 = 0.0f, a1 = 0.0f, a2 = 0.0f, a3 = 0.0f;
    int s0 = (g < deg)     ? csr_src[start + g]     : 0;
    int s1 = (g + 4 < deg) ? csr_src[start + g + 4] : 0;
    for (int j = g; j < deg; j += 8) {
        int p0 = (j + 8  < deg) ? csr_src[start + j + 8]  : 0;
        int p1 = (j + 12 < deg) ? csr_src[start + j + 12] : 0;
        ushort4 v0 = *(const ushort4*)&hsb[s0 * HID_DIM + l * 4];
        bool have1 = (j + 4 < deg);
        ushort4 v1;
        if (have1) v1 = *(const ushort4*)&hsb[s1 * HID_DIM + l * 4];
        a0 += bf2f(v0.x); a1 += bf2f(v0.y); a2 += bf2f(v0.z); a3 += bf2f(v0.w);
        if (have1) {
            a0 += bf2f(v1.x); a1 += bf2f(v1.y); a2 += bf2f(v1.z); a3 += bf2f(v1.w);
        }
        s0 = p0; s1 = p1;
    }
    // combine the 4 edge-groups (dims identical across groups)
    a0 += __shfl_xor(a0, 16); a1 += __shfl_xor(a1, 16);
    a2 += __shfl_xor(a2, 16); a3 += __shfl_xor(a3, 16);
    a0 += __shfl_xor(a0, 32); a1 += __shfl_xor(a1, 32);
    a2 += __shfl_xor(a2, 32); a3 += __shfl_xor(a3, 32);

    // self-loop term
    ushort4 sv = *(const ushort4*)&hsb[node * HID_DIM + l * 4];
    a0 += bf2f(sv.x); a1 += bf2f(sv.y); a2 += bf2f(sv.z); a3 += bf2f(sv.w);

    float di = dinv[node];
    float4 bb = *(const float4*)&b1[l * 4];
    float t0 = fmaxf(fmaf(di, a0, bb.x), 0.0f);
    float t1 = fmaxf(fmaf(di, a1, bb.y), 0.0f);
    float t2 = fmaxf(fmaf(di, a2, bb.z), 0.0f);
    float t3 = fmaxf(fmaf(di, a3, bb.w), 0.0f);

    // W2 rows for dims l*4..l*4+3: [d][2] row-major
    float4 w01 = *(const float4*)&W2[l * 8];       // d0:{x,y} d1:{z,w}
    float4 w23 = *(const float4*)&W2[l * 8 + 4];   // d2:{x,y} d3:{z,w}
    float p0 = t0 * w01.x + t1 * w01.z + t2 * w23.x + t3 * w23.z;
    float p1 = t0 * w01.y + t1 * w01.w + t2 * w23.y + t3 * w23.w;
    // reduce over the 16 dim-quads (all 4 groups hold identical copies)
    p0 += __shfl_xor(p0, 1);  p1 += __shfl_xor(p1, 1);
    p0 += __shfl_xor(p0, 2);  p1 += __shfl_xor(p1, 2);
    p0 += __shfl_xor(p0, 4);  p1 += __shfl_xor(p1, 4);
    p0 += __shfl_xor(p0, 8);  p1 += __shfl_xor(p1, 8);

    if (lane == 0) {
        hs2[node * OUT_DIM + 0] = di * p0;
        hs2[node * OUT_DIM + 1] = di * p1;
    }
}

// ---------------- agg2: wave/node CSR gather d=2 + fused epilogue ----------------
__global__ __launch_bounds__(256) void agg2_kernel(const int* __restrict__ rowptr,
                                                   const int* __restrict__ cnt,
                                                   const int* __restrict__ csr_src,
                                                   const float* __restrict__ hs2,
                                                   const float* __restrict__ dinv,
                                                   const float* __restrict__ b2,
                                                   float* __restrict__ out, int n) {
    int node = blockIdx.x * 4 + (threadIdx.x >> 6);
    if (node >= n) return;
    int lane = threadIdx.x & 63;
    int start = rowptr[node];
    int deg = cnt[node];

    float a0 = 0.0f, a1 = 0.0f;
    for (int j = lane; j < deg; j += 64) {
        int s = csr_src[start + j];
        float2 v = *(const float2*)&hs2[s * OUT_DIM];
        a0 += v.x;
        a1 += v.y;
    }
#pragma unroll
    for (int off = 32; off > 0; off >>= 1) {
        a0 += __shfl_xor(a0, off);
        a1 += __shfl_xor(a1, off);
    }
    if (lane == 0) {
        float di = dinv[node];
        float2 self = *(const float2*)&hs2[node * OUT_DIM];
        out[node * OUT_DIM + 0] = di * (a0 + self.x) + b2[0];
        out[node * OUT_DIM + 1] = di * (a1 + self.y) + b2[1];
    }
}

extern "C" void kernel_launch(void* const* d_in, const int* in_sizes, int n_in,
                              void* d_out, int out_size, void* d_ws, size_t ws_size,
                              hipStream_t stream) {
    const float* x  = (const float*)d_in[0];
    const int*   ei = (const int*)d_in[1];     // [2][E], row 0 = src, row 1 = dst
    const float* W1 = (const float*)d_in[2];
    const float* b1 = (const float*)d_in[3];
    const float* W2 = (const float*)d_in[4];
    const float* b2 = (const float*)d_in[5];
    float* out = (float*)d_out;

    const int n = N_NODES;
    const int E = in_sizes[1] / 2;

    char* ws = (char*)d_ws;
    int*   gHist       = (int*)  (ws + 0);            // 1.6 KB
    int*   bucketStart = (int*)  (ws + (4u << 10));   // 1.6 KB
    int*   gCursor     = (int*)  (ws + (8u << 10));   // 1.6 KB
    int*   cnt         = (int*)  (ws + (1u << 20));   // 400 KB
    float* dinv        = (float*)(ws + (2u << 20));   // 400 KB
    int*   rowptr      = (int*)  (ws + (3u << 20));   // 400 KB
    float* hs2         = (float*)(ws + (4u << 20));   // 800 KB
    int*   part        = (int*)  (ws + (5u << 20));   // 12.8 MB
    int*   csr_src     = (int*)  (ws + (18u << 20));  // 12.8 MB
    unsigned short* hsb = (unsigned short*)(ws + (31u << 20));  // 12.8 MB

    hipMemsetAsync(gHist, 0, NB * sizeof(int), stream);

    hist_kernel<<<1024, 256, 0, stream>>>(ei + E, gHist, E);
    bscan_kernel<<<1, 512, 0, stream>>>(gHist, bucketStart, gCursor);
    part_kernel<<<(E + CHUNK - 1) / CHUNK, 512, 0, stream>>>(ei, gCursor, part, E);
    csr_kernel<<<NB, 256, 0, stream>>>(part, gHist, bucketStart, cnt, dinv, rowptr, csr_src, n);

    gemm1_kernel<<<(n + 63) / 64, 256, 0, stream>>>(x, W1, dinv, hsb, n);
    agg1_kernel<<<(n + 3) / 4, 256, 0, stream>>>(rowptr, cnt, csr_src, hsb, dinv, b1, W2, hs2, n);
    agg2_kernel<<<(n + 3) / 4, 256, 0, stream>>>(rowptr, cnt, csr_src, hs2, dinv, b2, out, n);
}

// Round 7
// 303.794 us; speedup vs baseline: 5.7572x; 1.1184x over previous
//
#include <hip/hip_runtime.h>
#include <hip/hip_bf16.h>

// GCN 2-layer surrogate. Bucketed counting-sort CSR + wave-per-node gather-reduce.
//   bucket = dst >> 8 (391 buckets x 256 nodes)
//   hist:  bucket histogram; bscan: bucket starts
//   part:  bin edges by bucket, emit packed int: src | (dst&255)<<20  (12.8 MB)
//   csr:   per bucket: LDS-staged edges, shfl-scan histogram -> cnt/dinv/rowptr,
//          bucket-local counting sort -> csr_src (12.8 MB)
//   gemm1: MFMA bf16: hs_bf16 = bf16( dinv[r] * (x @ W1) )   (12.8 MB table)
//   agg1:  wave per node; 8 edge-groups x 8 dims/lane, uint4 row gathers with
//          index prefetch; fused relu + (64->2) + pre-scale epilogue
//   agg2:  wave per node, lane-parallel edges on d=2 table; fused epilogue

#define N_NODES 100000
#define IN_DIM 128
#define HID_DIM 64
#define OUT_DIM 2
#define NB 391          // ceil(100000/256)
#define CHUNK 4096

typedef short bf16x8 __attribute__((ext_vector_type(8)));
typedef float f32x4 __attribute__((ext_vector_type(4)));

__device__ __forceinline__ unsigned short f2bf(float x) {
    unsigned int u = __float_as_uint(x);
    unsigned int r = (u + 0x7FFFu + ((u >> 16) & 1u)) >> 16;   // RNE
    return (unsigned short)r;
}
__device__ __forceinline__ float bflo(unsigned int u) { return __uint_as_float(u << 16); }
__device__ __forceinline__ float bfhi(unsigned int u) { return __uint_as_float(u & 0xFFFF0000u); }
__device__ __forceinline__ int wave_incl_scan(int v, int laneid) {
#pragma unroll
    for (int off = 1; off < 64; off <<= 1) {
        int u = __shfl_up(v, off);
        if (laneid >= off) v += u;
    }
    return v;
}

// ---------------- A1: bucket histogram ----------------
__global__ __launch_bounds__(256) void hist_kernel(const int* __restrict__ dst,
                                                   int* __restrict__ gHist, int E) {
    __shared__ int h[NB];
    for (int i = threadIdx.x; i < NB; i += 256) h[i] = 0;
    __syncthreads();
    for (int e = blockIdx.x * 256 + threadIdx.x; e < E; e += gridDim.x * 256)
        atomicAdd(&h[dst[e] >> 8], 1);
    __syncthreads();
    for (int i = threadIdx.x; i < NB; i += 256)
        if (h[i]) atomicAdd(&gHist[i], h[i]);
}

// ---------------- B: scan bucket counts ----------------
__global__ __launch_bounds__(512) void bscan_kernel(const int* __restrict__ gHist,
                                                    int* __restrict__ bucketStart,
                                                    int* __restrict__ gCursor) {
    __shared__ int wsum[8], wofs[8];
    int t = threadIdx.x;
    int lane = t & 63, wv = t >> 6;
    int v = (t < NB) ? gHist[t] : 0;
    int inc = wave_incl_scan(v, lane);
    if (lane == 63) wsum[wv] = inc;
    __syncthreads();
    if (t < 64) {
        int w = (t < 8) ? wsum[t] : 0;
        int wi = wave_incl_scan(w, t);
        if (t < 8) wofs[t] = wi - w;
    }
    __syncthreads();
    if (t < NB) {
        int st = inc - v + wofs[wv];
        bucketStart[t] = st;
        gCursor[t] = st;
    }
}

// ---------------- A2: partition edges into bucket-ordered packed ints ----------------
__global__ __launch_bounds__(512) void part_kernel(const int* __restrict__ ei,
                                                   int* __restrict__ gCursor,
                                                   int* __restrict__ part, int E) {
    __shared__ int hist[512], lrow[512], gbase[512], lcur[512];
    __shared__ int lpk[CHUNK];
    __shared__ short lbkt[CHUNK];
    __shared__ int wsum[8], wofs[8];
    const int t = threadIdx.x;
    const int lane = t & 63, wv = t >> 6;
    const int base = blockIdx.x * CHUNK;
    const int cntC = min(CHUNK, E - base);

    hist[t] = 0;
    __syncthreads();

    int s[8], d[8];
#pragma unroll
    for (int i = 0; i < 8; ++i) {
        int e = base + t + i * 512;
        if (e < E) {
            s[i] = ei[e];
            d[i] = ei[E + e];
            atomicAdd(&hist[d[i] >> 8], 1);
        }
    }
    __syncthreads();

    int v = hist[t];
    int inc = wave_incl_scan(v, lane);
    if (lane == 63) wsum[wv] = inc;
    __syncthreads();
    if (t < 64) {
        int w = (t < 8) ? wsum[t] : 0;
        int wi = wave_incl_scan(w, t);
        if (t < 8) wofs[t] = wi - w;
    }
    __syncthreads();
    int excl = inc - v + wofs[wv];
    if (t < NB && v > 0) gbase[t] = atomicAdd(&gCursor[t], v);
    lcur[t] = excl;
    lrow[t] = excl;                    // exclusive offsets for write-out
    __syncthreads();

#pragma unroll
    for (int i = 0; i < 8; ++i) {
        int e = base + t + i * 512;
        if (e < E) {
            int b = d[i] >> 8;
            int pos = atomicAdd(&lcur[b], 1);
            lpk[pos] = s[i] | ((d[i] & 255) << 20);
            lbkt[pos] = (short)b;
        }
    }
    __syncthreads();

    for (int i = t; i < cntC; i += 512) {
        int b = lbkt[i];
        part[gbase[b] + (i - lrow[b])] = lpk[i];
    }
}

// ---------------- C: per-bucket CSR finalize (cnt/dinv/rowptr + src sort) ----------------
__global__ __launch_bounds__(256) void csr_kernel(const int* __restrict__ part,
                                                  const int* __restrict__ gHist,
                                                  const int* __restrict__ bucketStart,
                                                  int* __restrict__ cnt,
                                                  float* __restrict__ dinv,
                                                  int* __restrict__ rowptr,
                                                  int* __restrict__ csr_src, int n) {
    __shared__ int lcnt[256], lrow[256], lcur[256];
    __shared__ int epk[8192];          // 32 KB staging
    __shared__ int wsum[4], wofs[4];
    const int b = blockIdx.x, t = threadIdx.x;
    const int lane = t & 63, wv = t >> 6;
    const int start = bucketStart[b];
    const int count = gHist[b];
    const int cap = min(count, 8192);

    lcnt[t] = 0;
    __syncthreads();
    for (int i = t; i < count; i += 256) {
        int p = part[start + i];
        if (i < 8192) epk[i] = p;
        atomicAdd(&lcnt[(p >> 20) & 255], 1);
    }
    __syncthreads();

    int v = lcnt[t];
    int inc = wave_incl_scan(v, lane);
    if (lane == 63) wsum[wv] = inc;
    __syncthreads();
    if (t < 64) {
        int w = (t < 4) ? wsum[t] : 0;
        int wi = wave_incl_scan(w, t);
        if (t < 4) wofs[t] = wi - w;
    }
    __syncthreads();
    int excl = inc - v + wofs[wv];
    int node = (b << 8) + t;
    if (node < n) {
        cnt[node] = v;
        dinv[node] = rsqrtf((float)v + 1.0f);
        rowptr[node] = start + excl;
    }
    lcur[t] = excl;
    __syncthreads();

    for (int i = t; i < cap; i += 256) {
        int p = epk[i];
        int pos = atomicAdd(&lcur[(p >> 20) & 255], 1);
        csr_src[start + pos] = p & 0xFFFFF;
    }
    for (int i = 8192 + t; i < count; i += 256) {     // rare tail
        int p = part[start + i];
        int pos = atomicAdd(&lcur[(p >> 20) & 255], 1);
        csr_src[start + pos] = p & 0xFFFFF;
    }
}

// ---------------- GEMM1 (MFMA bf16): hs_bf16 = bf16(dinv[r] * (x @ W1)) ----------------
// 64 rows/block, 4 waves, wave = 16 rows x 64 cols = 16 mfma_f32_16x16x32_bf16.
// LDS: sX [64 rows][128 k] bf16 (pad 136), sW = W1^T [64 c][128 k] bf16 (pad 136).
__global__ __launch_bounds__(256) void gemm1_kernel(const float* __restrict__ x,
                                                    const float* __restrict__ W1,
                                                    const float* __restrict__ dinv,
                                                    unsigned short* __restrict__ hsb, int n) {
    __shared__ unsigned short sX[64 * 136];   // 17.4 KB
    __shared__ unsigned short sW[64 * 136];   // 17.4 KB (transposed W1)
    const int tid = threadIdx.x;
    const int rbase = blockIdx.x * 64;

    // stage W1^T: read [k][c] coalesced as float4, scatter bf16 to [c][k]
    for (int i = tid; i < 2048; i += 256) {
        int k = i >> 4, cq = (i & 15) << 2;
        float4 v = ((const float4*)W1)[i];
        sW[(cq + 0) * 136 + k] = f2bf(v.x);
        sW[(cq + 1) * 136 + k] = f2bf(v.y);
        sW[(cq + 2) * 136 + k] = f2bf(v.z);
        sW[(cq + 3) * 136 + k] = f2bf(v.w);
    }
    // stage x rows as bf16 (row-major, pad 136)
    for (int i = tid; i < 2048; i += 256) {
        int r = i >> 5, kq = (i & 31) << 2;
        int gr = rbase + r;
        float4 v = make_float4(0.f, 0.f, 0.f, 0.f);
        if (gr < n) v = ((const float4*)x)[gr * 32 + (i & 31)];
        ushort4 u;
        u.x = f2bf(v.x); u.y = f2bf(v.y); u.z = f2bf(v.z); u.w = f2bf(v.w);
        *(ushort4*)&sX[r * 136 + kq] = u;
    }
    __syncthreads();

    const int wave = tid >> 6, lane = tid & 63;
    const int quad = lane >> 4, l16 = lane & 15;
    const int rowoff = wave * 16;

    f32x4 acc[4];
#pragma unroll
    for (int t = 0; t < 4; ++t) acc[t] = (f32x4){0.f, 0.f, 0.f, 0.f};

#pragma unroll
    for (int k0 = 0; k0 < 128; k0 += 32) {
        bf16x8 a = *(const bf16x8*)&sX[(rowoff + l16) * 136 + k0 + quad * 8];
#pragma unroll
        for (int t = 0; t < 4; ++t) {
            bf16x8 b = *(const bf16x8*)&sW[(t * 16 + l16) * 136 + k0 + quad * 8];
            acc[t] = __builtin_amdgcn_mfma_f32_16x16x32_bf16(a, b, acc[t], 0, 0, 0);
        }
    }

    // D layout: col = l16, row = quad*4 + reg
#pragma unroll
    for (int r = 0; r < 4; ++r) {
        int grow = rbase + rowoff + quad * 4 + r;
        if (grow < n) {
            float di = dinv[grow];
#pragma unroll
            for (int t = 0; t < 4; ++t)
                hsb[grow * HID_DIM + t * 16 + l16] = f2bf(acc[t][r] * di);
        }
    }
}

// ---------------- agg1: wave/node, 8 edge-groups x 8 dims, uint4 gathers ----------------
// lane = g*8 + l: group g handles edges j = g, g+8, ...; lane loads 16B = dims l*8..l*8+7.
__global__ __launch_bounds__(256) void agg1_kernel(const int* __restrict__ rowptr,
                                                   const int* __restrict__ cnt,
                                                   const int* __restrict__ csr_src,
                                                   const unsigned short* __restrict__ hsb,
                                                   const float* __restrict__ dinv,
                                                   const float* __restrict__ b1,
                                                   const float* __restrict__ W2,
                                                   float* __restrict__ hs2, int n) {
    int node = blockIdx.x * 4 + (threadIdx.x >> 6);
    if (node >= n) return;
    int lane = threadIdx.x & 63;
    int g = lane >> 3;        // edge group 0..7
    int l = lane & 7;         // dim octet 0..7
    int start = rowptr[node];
    int deg = cnt[node];

    float a[8] = {0.f, 0.f, 0.f, 0.f, 0.f, 0.f, 0.f, 0.f};
    int s0 = (g < deg) ? csr_src[start + g] : 0;
    for (int j = g; j < deg; j += 8) {
        int nx = (j + 8 < deg) ? csr_src[start + j + 8] : 0;
        uint4 raw = *(const uint4*)&hsb[(unsigned)s0 * HID_DIM + l * 8];
        a[0] += bflo(raw.x); a[1] += bfhi(raw.x);
        a[2] += bflo(raw.y); a[3] += bfhi(raw.y);
        a[4] += bflo(raw.z); a[5] += bfhi(raw.z);
        a[6] += bflo(raw.w); a[7] += bfhi(raw.w);
        s0 = nx;
    }
    // combine the 8 edge-groups (dim octets identical across groups)
#pragma unroll
    for (int off = 8; off <= 32; off <<= 1) {
#pragma unroll
        for (int i = 0; i < 8; ++i) a[i] += __shfl_xor(a[i], off);
    }

    // self-loop term
    {
        uint4 raw = *(const uint4*)&hsb[(unsigned)node * HID_DIM + l * 8];
        a[0] += bflo(raw.x); a[1] += bfhi(raw.x);
        a[2] += bflo(raw.y); a[3] += bfhi(raw.y);
        a[4] += bflo(raw.z); a[5] += bfhi(raw.z);
        a[6] += bflo(raw.w); a[7] += bfhi(raw.w);
    }

    float di = dinv[node];
    float4 bb0 = *(const float4*)&b1[l * 8];
    float4 bb1 = *(const float4*)&b1[l * 8 + 4];
    float t0 = fmaxf(fmaf(di, a[0], bb0.x), 0.0f);
    float t1 = fmaxf(fmaf(di, a[1], bb0.y), 0.0f);
    float t2 = fmaxf(fmaf(di, a[2], bb0.z), 0.0f);
    float t3 = fmaxf(fmaf(di, a[3], bb0.w), 0.0f);
    float t4 = fmaxf(fmaf(di, a[4], bb1.x), 0.0f);
    float t5 = fmaxf(fmaf(di, a[5], bb1.y), 0.0f);
    float t6 = fmaxf(fmaf(di, a[6], bb1.z), 0.0f);
    float t7 = fmaxf(fmaf(di, a[7], bb1.w), 0.0f);

    // W2 rows for dims l*8..l*8+7: [d][2] row-major -> 4 float4
    float4 w0 = *(const float4*)&W2[l * 16];
    float4 w1 = *(const float4*)&W2[l * 16 + 4];
    float4 w2 = *(const float4*)&W2[l * 16 + 8];
    float4 w3 = *(const float4*)&W2[l * 16 + 12];
    float p0 = t0 * w0.x + t1 * w0.z + t2 * w1.x + t3 * w1.z
             + t4 * w2.x + t5 * w2.z + t6 * w3.x + t7 * w3.z;
    float p1 = t0 * w0.y + t1 * w0.w + t2 * w1.y + t3 * w1.w
             + t4 * w2.y + t5 * w2.w + t6 * w3.y + t7 * w3.w;
    // reduce over the 8 dim-octets
    p0 += __shfl_xor(p0, 1);  p1 += __shfl_xor(p1, 1);
    p0 += __shfl_xor(p0, 2);  p1 += __shfl_xor(p1, 2);
    p0 += __shfl_xor(p0, 4);  p1 += __shfl_xor(p1, 4);

    if (lane == 0) {
        hs2[node * OUT_DIM + 0] = di * p0;
        hs2[node * OUT_DIM + 1] = di * p1;
    }
}

// ---------------- agg2: wave/node CSR gather d=2 + fused epilogue ----------------
__global__ __launch_bounds__(256) void agg2_kernel(const int* __restrict__ rowptr,
                                                   const int* __restrict__ cnt,
                                                   const int* __restrict__ csr_src,
                                                   const float* __restrict__ hs2,
                                                   const float* __restrict__ dinv,
                                                   const float* __restrict__ b2,
                                                   float* __restrict__ out, int n) {
    int node = blockIdx.x * 4 + (threadIdx.x >> 6);
    if (node >= n) return;
    int lane = threadIdx.x & 63;
    int start = rowptr[node];
    int deg = cnt[node];

    float a0 = 0.0f, a1 = 0.0f;
    for (int j = lane; j < deg; j += 64) {
        int s = csr_src[start + j];
        float2 v = *(const float2*)&hs2[s * OUT_DIM];
        a0 += v.x;
        a1 += v.y;
    }
#pragma unroll
    for (int off = 32; off > 0; off >>= 1) {
        a0 += __shfl_xor(a0, off);
        a1 += __shfl_xor(a1, off);
    }
    if (lane == 0) {
        float di = dinv[node];
        float2 self = *(const float2*)&hs2[node * OUT_DIM];
        out[node * OUT_DIM + 0] = di * (a0 + self.x) + b2[0];
        out[node * OUT_DIM + 1] = di * (a1 + self.y) + b2[1];
    }
}

extern "C" void kernel_launch(void* const* d_in, const int* in_sizes, int n_in,
                              void* d_out, int out_size, void* d_ws, size_t ws_size,
                              hipStream_t stream) {
    const float* x  = (const float*)d_in[0];
    const int*   ei = (const int*)d_in[1];     // [2][E], row 0 = src, row 1 = dst
    const float* W1 = (const float*)d_in[2];
    const float* b1 = (const float*)d_in[3];
    const float* W2 = (const float*)d_in[4];
    const float* b2 = (const float*)d_in[5];
    float* out = (float*)d_out;

    const int n = N_NODES;
    const int E = in_sizes[1] / 2;

    char* ws = (char*)d_ws;
    int*   gHist       = (int*)  (ws + 0);            // 1.6 KB
    int*   bucketStart = (int*)  (ws + (4u << 10));   // 1.6 KB
    int*   gCursor     = (int*)  (ws + (8u << 10));   // 1.6 KB
    int*   cnt         = (int*)  (ws + (1u << 20));   // 400 KB
    float* dinv        = (float*)(ws + (2u << 20));   // 400 KB
    int*   rowptr      = (int*)  (ws + (3u << 20));   // 400 KB
    float* hs2         = (float*)(ws + (4u << 20));   // 800 KB
    int*   part        = (int*)  (ws + (5u << 20));   // 12.8 MB
    int*   csr_src     = (int*)  (ws + (18u << 20));  // 12.8 MB
    unsigned short* hsb = (unsigned short*)(ws + (31u << 20));  // 12.8 MB

    hipMemsetAsync(gHist, 0, NB * sizeof(int), stream);

    hist_kernel<<<1024, 256, 0, stream>>>(ei + E, gHist, E);
    bscan_kernel<<<1, 512, 0, stream>>>(gHist, bucketStart, gCursor);
    part_kernel<<<(E + CHUNK - 1) / CHUNK, 512, 0, stream>>>(ei, gCursor, part, E);
    csr_kernel<<<NB, 256, 0, stream>>>(part, gHist, bucketStart, cnt, dinv, rowptr, csr_src, n);

    gemm1_kernel<<<(n + 63) / 64, 256, 0, stream>>>(x, W1, dinv, hsb, n);
    agg1_kernel<<<(n + 3) / 4, 256, 0, stream>>>(rowptr, cnt, csr_src, hsb, dinv, b1, W2, hs2, n);
    agg2_kernel<<<(n + 3) / 4, 256, 0, stream>>>(rowptr, cnt, csr_src, hs2, dinv, b2, out, n);
}

// Round 8
// 280.253 us; speedup vs baseline: 6.2408x; 1.0840x over previous
//
#include <hip/hip_runtime.h>
#include <hip/hip_bf16.h>

// GCN 2-layer surrogate. Bucketed counting-sort CSR + wave-per-node gather-reduce.
//   bucket = dst >> 8 (391 buckets x 256 nodes)
//   hist:  bucket histogram (int4 loads); bscan: bucket starts
//   part:  bin edges by bucket (int4 loads), emit packed int: src | (dst&255)<<20
//   csr:   per bucket (1024 thr): LDS-staged edges, shfl-scan histogram ->
//          cnt/dinv/rowptr, bucket-local counting sort -> csr_src
//   gemm1: MFMA bf16: hs_bf16 = bf16( dinv[r] * (x @ W1) )   (12.8 MB table)
//   agg1:  wave per node; 8 edge-groups x 8 dims/lane, TWO uint4 row gathers in
//          flight + index prefetch; fused relu + (64->2) + pre-scale epilogue
//   agg2:  wave per node, lane-parallel edges on d=2 table; fused epilogue

#define N_NODES 100000
#define IN_DIM 128
#define HID_DIM 64
#define OUT_DIM 2
#define NB 391          // ceil(100000/256)
#define CHUNK 4096

typedef short bf16x8 __attribute__((ext_vector_type(8)));
typedef float f32x4 __attribute__((ext_vector_type(4)));

__device__ __forceinline__ unsigned short f2bf(float x) {
    unsigned int u = __float_as_uint(x);
    unsigned int r = (u + 0x7FFFu + ((u >> 16) & 1u)) >> 16;   // RNE
    return (unsigned short)r;
}
__device__ __forceinline__ float bflo(unsigned int u) { return __uint_as_float(u << 16); }
__device__ __forceinline__ float bfhi(unsigned int u) { return __uint_as_float(u & 0xFFFF0000u); }
__device__ __forceinline__ int wave_incl_scan(int v, int laneid) {
#pragma unroll
    for (int off = 1; off < 64; off <<= 1) {
        int u = __shfl_up(v, off);
        if (laneid >= off) v += u;
    }
    return v;
}

// ---------------- A1: bucket histogram ----------------
__global__ __launch_bounds__(256) void hist_kernel(const int* __restrict__ dst,
                                                   int* __restrict__ gHist, int E) {
    __shared__ int h[NB];
    for (int i = threadIdx.x; i < NB; i += 256) h[i] = 0;
    __syncthreads();
    int nq = E >> 2;
    for (int i = blockIdx.x * 256 + threadIdx.x; i < nq; i += gridDim.x * 256) {
        int4 d = ((const int4*)dst)[i];
        atomicAdd(&h[d.x >> 8], 1);
        atomicAdd(&h[d.y >> 8], 1);
        atomicAdd(&h[d.z >> 8], 1);
        atomicAdd(&h[d.w >> 8], 1);
    }
    if (blockIdx.x == 0 && threadIdx.x < (E & 3))
        atomicAdd(&h[dst[(E & ~3) + threadIdx.x] >> 8], 1);
    __syncthreads();
    for (int i = threadIdx.x; i < NB; i += 256)
        if (h[i]) atomicAdd(&gHist[i], h[i]);
}

// ---------------- B: scan bucket counts ----------------
__global__ __launch_bounds__(512) void bscan_kernel(const int* __restrict__ gHist,
                                                    int* __restrict__ bucketStart,
                                                    int* __restrict__ gCursor) {
    __shared__ int wsum[8], wofs[8];
    int t = threadIdx.x;
    int lane = t & 63, wv = t >> 6;
    int v = (t < NB) ? gHist[t] : 0;
    int inc = wave_incl_scan(v, lane);
    if (lane == 63) wsum[wv] = inc;
    __syncthreads();
    if (t < 64) {
        int w = (t < 8) ? wsum[t] : 0;
        int wi = wave_incl_scan(w, t);
        if (t < 8) wofs[t] = wi - w;
    }
    __syncthreads();
    if (t < NB) {
        int st = inc - v + wofs[wv];
        bucketStart[t] = st;
        gCursor[t] = st;
    }
}

// ---------------- A2: partition edges into bucket-ordered packed ints ----------------
__global__ __launch_bounds__(512) void part_kernel(const int* __restrict__ ei,
                                                   int* __restrict__ gCursor,
                                                   int* __restrict__ part, int E) {
    __shared__ int hist[512], lrow[512], gbase[512], lcur[512];
    __shared__ int lpk[CHUNK];
    __shared__ short lbkt[CHUNK];
    __shared__ int wsum[8], wofs[8];
    const int t = threadIdx.x;
    const int lane = t & 63, wv = t >> 6;
    const int base = blockIdx.x * CHUNK;
    const int cntC = min(CHUNK, E - base);

    hist[t] = 0;
    __syncthreads();

    int s[8], d[8];
    bool val[8];
    if (base + CHUNK <= E) {
#pragma unroll
        for (int i = 0; i < 2; ++i) {
            int4 sv = ((const int4*)(ei + base))[t + i * 512];
            int4 dv = ((const int4*)(ei + E + base))[t + i * 512];
            s[i * 4 + 0] = sv.x; s[i * 4 + 1] = sv.y; s[i * 4 + 2] = sv.z; s[i * 4 + 3] = sv.w;
            d[i * 4 + 0] = dv.x; d[i * 4 + 1] = dv.y; d[i * 4 + 2] = dv.z; d[i * 4 + 3] = dv.w;
            val[i * 4 + 0] = val[i * 4 + 1] = val[i * 4 + 2] = val[i * 4 + 3] = true;
        }
    } else {
#pragma unroll
        for (int i = 0; i < 8; ++i) {
            int e = base + t + i * 512;
            val[i] = (e < E);
            if (val[i]) {
                s[i] = ei[e];
                d[i] = ei[E + e];
            }
        }
    }
#pragma unroll
    for (int i = 0; i < 8; ++i)
        if (val[i]) atomicAdd(&hist[d[i] >> 8], 1);
    __syncthreads();

    int v = hist[t];
    int inc = wave_incl_scan(v, lane);
    if (lane == 63) wsum[wv] = inc;
    __syncthreads();
    if (t < 64) {
        int w = (t < 8) ? wsum[t] : 0;
        int wi = wave_incl_scan(w, t);
        if (t < 8) wofs[t] = wi - w;
    }
    __syncthreads();
    int excl = inc - v + wofs[wv];
    if (t < NB && v > 0) gbase[t] = atomicAdd(&gCursor[t], v);
    lcur[t] = excl;
    lrow[t] = excl;                    // exclusive offsets for write-out
    __syncthreads();

#pragma unroll
    for (int i = 0; i < 8; ++i) {
        if (val[i]) {
            int b = d[i] >> 8;
            int pos = atomicAdd(&lcur[b], 1);
            lpk[pos] = s[i] | ((d[i] & 255) << 20);
            lbkt[pos] = (short)b;
        }
    }
    __syncthreads();

    for (int i = t; i < cntC; i += 512) {
        int b = lbkt[i];
        part[gbase[b] + (i - lrow[b])] = lpk[i];
    }
}

// ---------------- C: per-bucket CSR finalize (cnt/dinv/rowptr + src sort) ----------------
__global__ __launch_bounds__(1024) void csr_kernel(const int* __restrict__ part,
                                                   const int* __restrict__ gHist,
                                                   const int* __restrict__ bucketStart,
                                                   int* __restrict__ cnt,
                                                   float* __restrict__ dinv,
                                                   int* __restrict__ rowptr,
                                                   int* __restrict__ csr_src, int n) {
    __shared__ int lcnt[256], lcur[256];
    __shared__ int epk[8192];          // 32 KB staging
    __shared__ int wsum[4], wofs[4];
    const int b = blockIdx.x, t = threadIdx.x;
    const int start = bucketStart[b];
    const int count = gHist[b];
    const int cap = min(count, 8192);

    if (t < 256) lcnt[t] = 0;
    __syncthreads();
    for (int i = t; i < count; i += 1024) {
        int p = part[start + i];
        if (i < 8192) epk[i] = p;
        atomicAdd(&lcnt[(p >> 20) & 255], 1);
    }
    __syncthreads();

    int v = 0, inc = 0;
    const int lane = t & 63, wv = t >> 6;
    if (t < 256) {
        v = lcnt[t];
        inc = wave_incl_scan(v, lane);
        if (lane == 63) wsum[wv] = inc;
    }
    __syncthreads();
    if (t < 64) {
        int w = (t < 4) ? wsum[t] : 0;
        int wi = wave_incl_scan(w, t);
        if (t < 4) wofs[t] = wi - w;
    }
    __syncthreads();
    if (t < 256) {
        int excl = inc - v + wofs[wv];
        int node = (b << 8) + t;
        if (node < n) {
            cnt[node] = v;
            dinv[node] = rsqrtf((float)v + 1.0f);
            rowptr[node] = start + excl;
        }
        lcur[t] = excl;
    }
    __syncthreads();

    for (int i = t; i < cap; i += 1024) {
        int p = epk[i];
        int pos = atomicAdd(&lcur[(p >> 20) & 255], 1);
        csr_src[start + pos] = p & 0xFFFFF;
    }
    for (int i = 8192 + t; i < count; i += 1024) {    // rare tail
        int p = part[start + i];
        int pos = atomicAdd(&lcur[(p >> 20) & 255], 1);
        csr_src[start + pos] = p & 0xFFFFF;
    }
}

// ---------------- GEMM1 (MFMA bf16): hs_bf16 = bf16(dinv[r] * (x @ W1)) ----------------
__global__ __launch_bounds__(256) void gemm1_kernel(const float* __restrict__ x,
                                                    const float* __restrict__ W1,
                                                    const float* __restrict__ dinv,
                                                    unsigned short* __restrict__ hsb, int n) {
    __shared__ unsigned short sX[64 * 136];   // 17.4 KB
    __shared__ unsigned short sW[64 * 136];   // 17.4 KB (transposed W1)
    const int tid = threadIdx.x;
    const int rbase = blockIdx.x * 64;

    // stage W1^T: read [k][c] coalesced as float4, scatter bf16 to [c][k]
    for (int i = tid; i < 2048; i += 256) {
        int k = i >> 4, cq = (i & 15) << 2;
        float4 v = ((const float4*)W1)[i];
        sW[(cq + 0) * 136 + k] = f2bf(v.x);
        sW[(cq + 1) * 136 + k] = f2bf(v.y);
        sW[(cq + 2) * 136 + k] = f2bf(v.z);
        sW[(cq + 3) * 136 + k] = f2bf(v.w);
    }
    // stage x rows as bf16 (row-major, pad 136)
    for (int i = tid; i < 2048; i += 256) {
        int r = i >> 5, kq = (i & 31) << 2;
        int gr = rbase + r;
        float4 v = make_float4(0.f, 0.f, 0.f, 0.f);
        if (gr < n) v = ((const float4*)x)[gr * 32 + (i & 31)];
        ushort4 u;
        u.x = f2bf(v.x); u.y = f2bf(v.y); u.z = f2bf(v.z); u.w = f2bf(v.w);
        *(ushort4*)&sX[r * 136 + kq] = u;
    }
    __syncthreads();

    const int wave = tid >> 6, lane = tid & 63;
    const int quad = lane >> 4, l16 = lane & 15;
    const int rowoff = wave * 16;

    f32x4 acc[4];
#pragma unroll
    for (int t = 0; t < 4; ++t) acc[t] = (f32x4){0.f, 0.f, 0.f, 0.f};

#pragma unroll
    for (int k0 = 0; k0 < 128; k0 += 32) {
        bf16x8 a = *(const bf16x8*)&sX[(rowoff + l16) * 136 + k0 + quad * 8];
#pragma unroll
        for (int t = 0; t < 4; ++t) {
            bf16x8 b = *(const bf16x8*)&sW[(t * 16 + l16) * 136 + k0 + quad * 8];
            acc[t] = __builtin_amdgcn_mfma_f32_16x16x32_bf16(a, b, acc[t], 0, 0, 0);
        }
    }

    // D layout: col = l16, row = quad*4 + reg
#pragma unroll
    for (int r = 0; r < 4; ++r) {
        int grow = rbase + rowoff + quad * 4 + r;
        if (grow < n) {
            float di = dinv[grow];
#pragma unroll
            for (int t = 0; t < 4; ++t)
                hsb[grow * HID_DIM + t * 16 + l16] = f2bf(acc[t][r] * di);
        }
    }
}

// ---------------- agg1: wave/node, 2 uint4 gathers in flight, fused epilogue ----------------
// lane = g*8 + l: group g handles edges j = g, g+8, ...; lane loads 16B = dims l*8..l*8+7.
__global__ __launch_bounds__(256) void agg1_kernel(const int* __restrict__ rowptr,
                                                   const int* __restrict__ cnt,
                                                   const int* __restrict__ csr_src,
                                                   const unsigned short* __restrict__ hsb,
                                                   const float* __restrict__ dinv,
                                                   const float* __restrict__ b1,
                                                   const float* __restrict__ W2,
                                                   float* __restrict__ hs2, int n) {
    int node = blockIdx.x * 4 + (threadIdx.x >> 6);
    if (node >= n) return;
    int lane = threadIdx.x & 63;
    int g = lane >> 3;        // edge group 0..7
    int l = lane & 7;         // dim octet 0..7
    int start = rowptr[node];
    int deg = cnt[node];

    float a[8] = {0.f, 0.f, 0.f, 0.f, 0.f, 0.f, 0.f, 0.f};
    int s0 = (g < deg)     ? csr_src[start + g]     : 0;
    int s1 = (g + 8 < deg) ? csr_src[start + g + 8] : 0;
    for (int j = g; j < deg; j += 16) {
        int p0 = (j + 16 < deg) ? csr_src[start + j + 16] : 0;
        int p1 = (j + 24 < deg) ? csr_src[start + j + 24] : 0;
        uint4 r0 = *(const uint4*)&hsb[(unsigned)s0 * HID_DIM + l * 8];
        uint4 r1 = *(const uint4*)&hsb[(unsigned)s1 * HID_DIM + l * 8];
        float m1 = (j + 8 < deg) ? 1.0f : 0.0f;
        a[0] += bflo(r0.x); a[1] += bfhi(r0.x);
        a[2] += bflo(r0.y); a[3] += bfhi(r0.y);
        a[4] += bflo(r0.z); a[5] += bfhi(r0.z);
        a[6] += bflo(r0.w); a[7] += bfhi(r0.w);
        a[0] = fmaf(m1, bflo(r1.x), a[0]); a[1] = fmaf(m1, bfhi(r1.x), a[1]);
        a[2] = fmaf(m1, bflo(r1.y), a[2]); a[3] = fmaf(m1, bfhi(r1.y), a[3]);
        a[4] = fmaf(m1, bflo(r1.z), a[4]); a[5] = fmaf(m1, bfhi(r1.z), a[5]);
        a[6] = fmaf(m1, bflo(r1.w), a[6]); a[7] = fmaf(m1, bfhi(r1.w), a[7]);
        s0 = p0; s1 = p1;
    }
    // combine the 8 edge-groups (dim octets identical across groups)
#pragma unroll
    for (int off = 8; off <= 32; off <<= 1) {
#pragma unroll
        for (int i = 0; i < 8; ++i) a[i] += __shfl_xor(a[i], off);
    }

    // self-loop term
    {
        uint4 raw = *(const uint4*)&hsb[(unsigned)node * HID_DIM + l * 8];
        a[0] += bflo(raw.x); a[1] += bfhi(raw.x);
        a[2] += bflo(raw.y); a[3] += bfhi(raw.y);
        a[4] += bflo(raw.z); a[5] += bfhi(raw.z);
        a[6] += bflo(raw.w); a[7] += bfhi(raw.w);
    }

    float di = dinv[node];
    float4 bb0 = *(const float4*)&b1[l * 8];
    float4 bb1 = *(const float4*)&b1[l * 8 + 4];
    float t0 = fmaxf(fmaf(di, a[0], bb0.x), 0.0f);
    float t1 = fmaxf(fmaf(di, a[1], bb0.y), 0.0f);
    float t2 = fmaxf(fmaf(di, a[2], bb0.z), 0.0f);
    float t3 = fmaxf(fmaf(di, a[3], bb0.w), 0.0f);
    float t4 = fmaxf(fmaf(di, a[4], bb1.x), 0.0f);
    float t5 = fmaxf(fmaf(di, a[5], bb1.y), 0.0f);
    float t6 = fmaxf(fmaf(di, a[6], bb1.z), 0.0f);
    float t7 = fmaxf(fmaf(di, a[7], bb1.w), 0.0f);

    // W2 rows for dims l*8..l*8+7: [d][2] row-major -> 4 float4
    float4 w0 = *(const float4*)&W2[l * 16];
    float4 w1 = *(const float4*)&W2[l * 16 + 4];
    float4 w2 = *(const float4*)&W2[l * 16 + 8];
    float4 w3 = *(const float4*)&W2[l * 16 + 12];
    float p0 = t0 * w0.x + t1 * w0.z + t2 * w1.x + t3 * w1.z
             + t4 * w2.x + t5 * w2.z + t6 * w3.x + t7 * w3.z;
    float p1 = t0 * w0.y + t1 * w0.w + t2 * w1.y + t3 * w1.w
             + t4 * w2.y + t5 * w2.w + t6 * w3.y + t7 * w3.w;
    // reduce over the 8 dim-octets
    p0 += __shfl_xor(p0, 1);  p1 += __shfl_xor(p1, 1);
    p0 += __shfl_xor(p0, 2);  p1 += __shfl_xor(p1, 2);
    p0 += __shfl_xor(p0, 4);  p1 += __shfl_xor(p1, 4);

    if (lane == 0) {
        hs2[node * OUT_DIM + 0] = di * p0;
        hs2[node * OUT_DIM + 1] = di * p1;
    }
}

// ---------------- agg2: wave/node CSR gather d=2 + fused epilogue ----------------
__global__ __launch_bounds__(256) void agg2_kernel(const int* __restrict__ rowptr,
                                                   const int* __restrict__ cnt,
                                                   const int* __restrict__ csr_src,
                                                   const float* __restrict__ hs2,
                                                   const float* __restrict__ dinv,
                                                   const float* __restrict__ b2,
                                                   float* __restrict__ out, int n) {
    int node = blockIdx.x * 4 + (threadIdx.x >> 6);
    if (node >= n) return;
    int lane = threadIdx.x & 63;
    int start = rowptr[node];
    int deg = cnt[node];

    float a0 = 0.0f, a1 = 0.0f;
    for (int j = lane; j < deg; j += 64) {
        int s = csr_src[start + j];
        float2 v = *(const float2*)&hs2[s * OUT_DIM];
        a0 += v.x;
        a1 += v.y;
    }
#pragma unroll
    for (int off = 32; off > 0; off >>= 1) {
        a0 += __shfl_xor(a0, off);
        a1 += __shfl_xor(a1, off);
    }
    if (lane == 0) {
        float di = dinv[node];
        float2 self = *(const float2*)&hs2[node * OUT_DIM];
        out[node * OUT_DIM + 0] = di * (a0 + self.x) + b2[0];
        out[node * OUT_DIM + 1] = di * (a1 + self.y) + b2[1];
    }
}

extern "C" void kernel_launch(void* const* d_in, const int* in_sizes, int n_in,
                              void* d_out, int out_size, void* d_ws, size_t ws_size,
                              hipStream_t stream) {
    const float* x  = (const float*)d_in[0];
    const int*   ei = (const int*)d_in[1];     // [2][E], row 0 = src, row 1 = dst
    const float* W1 = (const float*)d_in[2];
    const float* b1 = (const float*)d_in[3];
    const float* W2 = (const float*)d_in[4];
    const float* b2 = (const float*)d_in[5];
    float* out = (float*)d_out;

    const int n = N_NODES;
    const int E = in_sizes[1] / 2;

    char* ws = (char*)d_ws;
    int*   gHist       = (int*)  (ws + 0);            // 1.6 KB
    int*   bucketStart = (int*)  (ws + (4u << 10));   // 1.6 KB
    int*   gCursor     = (int*)  (ws + (8u << 10));   // 1.6 KB
    int*   cnt         = (int*)  (ws + (1u << 20));   // 400 KB
    float* dinv        = (float*)(ws + (2u << 20));   // 400 KB
    int*   rowptr      = (int*)  (ws + (3u << 20));   // 400 KB
    float* hs2         = (float*)(ws + (4u << 20));   // 800 KB
    int*   part        = (int*)  (ws + (5u << 20));   // 12.8 MB
    int*   csr_src     = (int*)  (ws + (18u << 20));  // 12.8 MB
    unsigned short* hsb = (unsigned short*)(ws + (31u << 20));  // 12.8 MB

    hipMemsetAsync(gHist, 0, NB * sizeof(int), stream);

    hist_kernel<<<1024, 256, 0, stream>>>(ei + E, gHist, E);
    bscan_kernel<<<1, 512, 0, stream>>>(gHist, bucketStart, gCursor);
    part_kernel<<<(E + CHUNK - 1) / CHUNK, 512, 0, stream>>>(ei, gCursor, part, E);
    csr_kernel<<<NB, 1024, 0, stream>>>(part, gHist, bucketStart, cnt, dinv, rowptr, csr_src, n);

    gemm1_kernel<<<(n + 63) / 64, 256, 0, stream>>>(x, W1, dinv, hsb, n);
    agg1_kernel<<<(n + 3) / 4, 256, 0, stream>>>(rowptr, cnt, csr_src, hsb, dinv, b1, W2, hs2, n);
    agg2_kernel<<<(n + 3) / 4, 256, 0, stream>>>(rowptr, cnt, csr_src, hs2, dinv, b2, out, n);
}

// Round 9
// 249.892 us; speedup vs baseline: 6.9991x; 1.1215x over previous
//
#include <hip/hip_runtime.h>
#include <hip/hip_bf16.h>

// GCN 2-layer surrogate. Fixed-capacity bucketed counting-sort CSR +
// wave-per-node gather-reduce.
//   bucket = dst >> 8 (391 buckets x 256 nodes), fixed capacity BCAP/bucket
//   part:  bin edges by bucket (int4 loads), claim runs from zeroed gCursor,
//          emit packed int: src | (dst&255)<<20 into bucket region b*BCAP
//   csr:   per bucket (1024 thr): LDS-staged edges, per-wave histograms ->
//          cnt/dinv/rowptr, per-wave scatter bases -> csr_src
//   gemm1: MFMA bf16: hs_bf16 = bf16( dinv[r] * (x @ W1) )   (12.8 MB table)
//   agg1:  wave per node; 8 edge-groups x 8 dims/lane, TWO uint4 row gathers in
//          flight + index prefetch; fused relu + (64->2) + pre-scale epilogue
//   agg2:  wave per node, lane-parallel edges on d=2 table; fused epilogue

#define N_NODES 100000
#define IN_DIM 128
#define HID_DIM 64
#define OUT_DIM 2
#define NB 391          // ceil(100000/256)
#define BCAP 12288      // slots per bucket (mean 8184, sigma ~90 -> 45 sigma)
#define CHUNK 8192

typedef short bf16x8 __attribute__((ext_vector_type(8)));
typedef float f32x4 __attribute__((ext_vector_type(4)));

__device__ __forceinline__ unsigned short f2bf(float x) {
    unsigned int u = __float_as_uint(x);
    unsigned int r = (u + 0x7FFFu + ((u >> 16) & 1u)) >> 16;   // RNE
    return (unsigned short)r;
}
__device__ __forceinline__ float bflo(unsigned int u) { return __uint_as_float(u << 16); }
__device__ __forceinline__ float bfhi(unsigned int u) { return __uint_as_float(u & 0xFFFF0000u); }
__device__ __forceinline__ int wave_incl_scan(int v, int laneid) {
#pragma unroll
    for (int off = 1; off < 64; off <<= 1) {
        int u = __shfl_up(v, off);
        if (laneid >= off) v += u;
    }
    return v;
}

// ---------------- part: partition edges into fixed-capacity bucket regions ----------------
__global__ __launch_bounds__(512) void part_kernel(const int* __restrict__ ei,
                                                   int* __restrict__ gCursor,
                                                   int* __restrict__ part, int E) {
    __shared__ int hist[512], lrow[512], gbase[512], lcur[512];
    __shared__ int lpk[CHUNK];
    __shared__ short lbkt[CHUNK];
    __shared__ int wsum[8], wofs[8];
    const int t = threadIdx.x;
    const int lane = t & 63, wv = t >> 6;
    const int base = blockIdx.x * CHUNK;
    const int cntC = min(CHUNK, E - base);

    hist[t] = 0;
    __syncthreads();

    int s[16], d[16];
    bool val[16];
    if (base + CHUNK <= E) {
#pragma unroll
        for (int i = 0; i < 4; ++i) {
            int4 sv = ((const int4*)(ei + base))[t + i * 512];
            int4 dv = ((const int4*)(ei + E + base))[t + i * 512];
            s[i * 4 + 0] = sv.x; s[i * 4 + 1] = sv.y; s[i * 4 + 2] = sv.z; s[i * 4 + 3] = sv.w;
            d[i * 4 + 0] = dv.x; d[i * 4 + 1] = dv.y; d[i * 4 + 2] = dv.z; d[i * 4 + 3] = dv.w;
            val[i * 4 + 0] = val[i * 4 + 1] = val[i * 4 + 2] = val[i * 4 + 3] = true;
        }
    } else {
#pragma unroll
        for (int i = 0; i < 16; ++i) {
            int e = base + t + i * 512;
            val[i] = (e < E);
            if (val[i]) {
                s[i] = ei[e];
                d[i] = ei[E + e];
            }
        }
    }
#pragma unroll
    for (int i = 0; i < 16; ++i)
        if (val[i]) atomicAdd(&hist[d[i] >> 8], 1);
    __syncthreads();

    int v = hist[t];
    int inc = wave_incl_scan(v, lane);
    if (lane == 63) wsum[wv] = inc;
    __syncthreads();
    if (t < 64) {
        int w = (t < 8) ? wsum[t] : 0;
        int wi = wave_incl_scan(w, t);
        if (t < 8) wofs[t] = wi - w;
    }
    __syncthreads();
    int excl = inc - v + wofs[wv];
    if (t < NB && v > 0) {
        int old = atomicAdd(&gCursor[t], v);
        gbase[t] = t * BCAP + old;
    }
    lcur[t] = excl;
    lrow[t] = excl;                    // exclusive offsets for write-out
    __syncthreads();

#pragma unroll
    for (int i = 0; i < 16; ++i) {
        if (val[i]) {
            int b = d[i] >> 8;
            int pos = atomicAdd(&lcur[b], 1);
            lpk[pos] = s[i] | ((d[i] & 255) << 20);
            lbkt[pos] = (short)b;
        }
    }
    __syncthreads();

    for (int i = t; i < cntC; i += 512) {
        int b = lbkt[i];
        int g = gbase[b] + (i - lrow[b]);
        if (g < (b + 1) * BCAP)        // overflow guard (never in practice)
            part[g] = lpk[i];
    }
}

// ---------------- csr: per-bucket CSR finalize (cnt/dinv/rowptr + src sort) ----------------
// per-wave histograms + per-wave scatter bases: LDS-atomic contention is wave-private.
__global__ __launch_bounds__(1024) void csr_kernel(const int* __restrict__ part,
                                                   const int* __restrict__ gCursor,
                                                   int* __restrict__ cnt,
                                                   float* __restrict__ dinv,
                                                   int* __restrict__ rowptr,
                                                   int* __restrict__ csr_src, int n) {
    __shared__ int epk[BCAP];          // 48 KB staging (whole bucket)
    __shared__ int wcnt[16][256];      // 16 KB: per-wave hist, then per-wave bases
    __shared__ int wsum[4], wofs[4];
    const int b = blockIdx.x, t = threadIdx.x;
    const int lane = t & 63, wv = t >> 6;
    const int start = b * BCAP;
    const int count = min(gCursor[b], BCAP);

    for (int i = t; i < 16 * 256; i += 1024) ((int*)wcnt)[i] = 0;
    __syncthreads();
    for (int i = t; i < count; i += 1024) {
        int p = part[start + i];
        epk[i] = p;
        atomicAdd(&wcnt[wv][(p >> 20) & 255], 1);
    }
    __syncthreads();

    int v = 0;
    if (t < 256) {
        int sum = 0;
#pragma unroll
        for (int w = 0; w < 16; ++w) sum += wcnt[w][t];
        v = sum;
    }
    int inc = 0;
    if (t < 256) {
        inc = wave_incl_scan(v, lane);
        if (lane == 63) wsum[wv] = inc;
    }
    __syncthreads();
    if (t < 64) {
        int w = (t < 4) ? wsum[t] : 0;
        int wi = wave_incl_scan(w, t);
        if (t < 4) wofs[t] = wi - w;
    }
    __syncthreads();
    if (t < 256) {
        int excl = inc - v + wofs[wv];
        int node = (b << 8) + t;
        if (node < n) {
            cnt[node] = v;
            dinv[node] = rsqrtf((float)v + 1.0f);
            rowptr[node] = start + excl;
        }
        int run = excl;                // per-wave scatter bases, in place
#pragma unroll
        for (int w = 0; w < 16; ++w) {
            int c = wcnt[w][t];
            wcnt[w][t] = run;
            run += c;
        }
    }
    __syncthreads();

    for (int i = t; i < count; i += 1024) {
        int p = epk[i];
        int pos = atomicAdd(&wcnt[wv][(p >> 20) & 255], 1);
        csr_src[start + pos] = p & 0xFFFFF;
    }
}

// ---------------- GEMM1 (MFMA bf16): hs_bf16 = bf16(dinv[r] * (x @ W1)) ----------------
__global__ __launch_bounds__(256) void gemm1_kernel(const float* __restrict__ x,
                                                    const float* __restrict__ W1,
                                                    const float* __restrict__ dinv,
                                                    unsigned short* __restrict__ hsb, int n) {
    __shared__ unsigned short sX[64 * 136];   // 17.4 KB
    __shared__ unsigned short sW[64 * 136];   // 17.4 KB (transposed W1)
    const int tid = threadIdx.x;
    const int rbase = blockIdx.x * 64;

    // stage W1^T: read [k][c] coalesced as float4, scatter bf16 to [c][k]
    for (int i = tid; i < 2048; i += 256) {
        int k = i >> 4, cq = (i & 15) << 2;
        float4 v = ((const float4*)W1)[i];
        sW[(cq + 0) * 136 + k] = f2bf(v.x);
        sW[(cq + 1) * 136 + k] = f2bf(v.y);
        sW[(cq + 2) * 136 + k] = f2bf(v.z);
        sW[(cq + 3) * 136 + k] = f2bf(v.w);
    }
    // stage x rows as bf16 (row-major, pad 136)
    for (int i = tid; i < 2048; i += 256) {
        int r = i >> 5, kq = (i & 31) << 2;
        int gr = rbase + r;
        float4 v = make_float4(0.f, 0.f, 0.f, 0.f);
        if (gr < n) v = ((const float4*)x)[gr * 32 + (i & 31)];
        ushort4 u;
        u.x = f2bf(v.x); u.y = f2bf(v.y); u.z = f2bf(v.z); u.w = f2bf(v.w);
        *(ushort4*)&sX[r * 136 + kq] = u;
    }
    __syncthreads();

    const int wave = tid >> 6, lane = tid & 63;
    const int quad = lane >> 4, l16 = lane & 15;
    const int rowoff = wave * 16;

    f32x4 acc[4];
#pragma unroll
    for (int t = 0; t < 4; ++t) acc[t] = (f32x4){0.f, 0.f, 0.f, 0.f};

#pragma unroll
    for (int k0 = 0; k0 < 128; k0 += 32) {
        bf16x8 a = *(const bf16x8*)&sX[(rowoff + l16) * 136 + k0 + quad * 8];
#pragma unroll
        for (int t = 0; t < 4; ++t) {
            bf16x8 b = *(const bf16x8*)&sW[(t * 16 + l16) * 136 + k0 + quad * 8];
            acc[t] = __builtin_amdgcn_mfma_f32_16x16x32_bf16(a, b, acc[t], 0, 0, 0);
        }
    }

    // D layout: col = l16, row = quad*4 + reg
#pragma unroll
    for (int r = 0; r < 4; ++r) {
        int grow = rbase + rowoff + quad * 4 + r;
        if (grow < n) {
            float di = dinv[grow];
#pragma unroll
            for (int t = 0; t < 4; ++t)
                hsb[grow * HID_DIM + t * 16 + l16] = f2bf(acc[t][r] * di);
        }
    }
}

// ---------------- agg1: wave/node, 2 uint4 gathers in flight, fused epilogue ----------------
// lane = g*8 + l: group g handles edges j = g, g+8, ...; lane loads 16B = dims l*8..l*8+7.
__global__ __launch_bounds__(256) void agg1_kernel(const int* __restrict__ rowptr,
                                                   const int* __restrict__ cnt,
                                                   const int* __restrict__ csr_src,
                                                   const unsigned short* __restrict__ hsb,
                                                   const float* __restrict__ dinv,
                                                   const float* __restrict__ b1,
                                                   const float* __restrict__ W2,
                                                   float* __restrict__ hs2, int n) {
    int node = blockIdx.x * 4 + (threadIdx.x >> 6);
    if (node >= n) return;
    int lane = threadIdx.x & 63;
    int g = lane >> 3;        // edge group 0..7
    int l = lane & 7;         // dim octet 0..7
    int start = rowptr[node];
    int deg = cnt[node];

    float a[8] = {0.f, 0.f, 0.f, 0.f, 0.f, 0.f, 0.f, 0.f};
    int s0 = (g < deg)     ? csr_src[start + g]     : 0;
    int s1 = (g + 8 < deg) ? csr_src[start + g + 8] : 0;
    for (int j = g; j < deg; j += 16) {
        int p0 = (j + 16 < deg) ? csr_src[start + j + 16] : 0;
        int p1 = (j + 24 < deg) ? csr_src[start + j + 24] : 0;
        uint4 r0 = *(const uint4*)&hsb[(unsigned)s0 * HID_DIM + l * 8];
        uint4 r1 = *(const uint4*)&hsb[(unsigned)s1 * HID_DIM + l * 8];
        float m1 = (j + 8 < deg) ? 1.0f : 0.0f;
        a[0] += bflo(r0.x); a[1] += bfhi(r0.x);
        a[2] += bflo(r0.y); a[3] += bfhi(r0.y);
        a[4] += bflo(r0.z); a[5] += bfhi(r0.z);
        a[6] += bflo(r0.w); a[7] += bfhi(r0.w);
        a[0] = fmaf(m1, bflo(r1.x), a[0]); a[1] = fmaf(m1, bfhi(r1.x), a[1]);
        a[2] = fmaf(m1, bflo(r1.y), a[2]); a[3] = fmaf(m1, bfhi(r1.y), a[3]);
        a[4] = fmaf(m1, bflo(r1.z), a[4]); a[5] = fmaf(m1, bfhi(r1.z), a[5]);
        a[6] = fmaf(m1, bflo(r1.w), a[6]); a[7] = fmaf(m1, bfhi(r1.w), a[7]);
        s0 = p0; s1 = p1;
    }
    // combine the 8 edge-groups (dim octets identical across groups)
#pragma unroll
    for (int off = 8; off <= 32; off <<= 1) {
#pragma unroll
        for (int i = 0; i < 8; ++i) a[i] += __shfl_xor(a[i], off);
    }

    // self-loop term
    {
        uint4 raw = *(const uint4*)&hsb[(unsigned)node * HID_DIM + l * 8];
        a[0] += bflo(raw.x); a[1] += bfhi(raw.x);
        a[2] += bflo(raw.y); a[3] += bfhi(raw.y);
        a[4] += bflo(raw.z); a[5] += bfhi(raw.z);
        a[6] += bflo(raw.w); a[7] += bfhi(raw.w);
    }

    float di = dinv[node];
    float4 bb0 = *(const float4*)&b1[l * 8];
    float4 bb1 = *(const float4*)&b1[l * 8 + 4];
    float t0 = fmaxf(fmaf(di, a[0], bb0.x), 0.0f);
    float t1 = fmaxf(fmaf(di, a[1], bb0.y), 0.0f);
    float t2 = fmaxf(fmaf(di, a[2], bb0.z), 0.0f);
    float t3 = fmaxf(fmaf(di, a[3], bb0.w), 0.0f);
    float t4 = fmaxf(fmaf(di, a[4], bb1.x), 0.0f);
    float t5 = fmaxf(fmaf(di, a[5], bb1.y), 0.0f);
    float t6 = fmaxf(fmaf(di, a[6], bb1.z), 0.0f);
    float t7 = fmaxf(fmaf(di, a[7], bb1.w), 0.0f);

    // W2 rows for dims l*8..l*8+7: [d][2] row-major -> 4 float4
    float4 w0 = *(const float4*)&W2[l * 16];
    float4 w1 = *(const float4*)&W2[l * 16 + 4];
    float4 w2 = *(const float4*)&W2[l * 16 + 8];
    float4 w3 = *(const float4*)&W2[l * 16 + 12];
    float p0 = t0 * w0.x + t1 * w0.z + t2 * w1.x + t3 * w1.z
             + t4 * w2.x + t5 * w2.z + t6 * w3.x + t7 * w3.z;
    float p1 = t0 * w0.y + t1 * w0.w + t2 * w1.y + t3 * w1.w
             + t4 * w2.y + t5 * w2.w + t6 * w3.y + t7 * w3.w;
    // reduce over the 8 dim-octets
    p0 += __shfl_xor(p0, 1);  p1 += __shfl_xor(p1, 1);
    p0 += __shfl_xor(p0, 2);  p1 += __shfl_xor(p1, 2);
    p0 += __shfl_xor(p0, 4);  p1 += __shfl_xor(p1, 4);

    if (lane == 0) {
        hs2[node * OUT_DIM + 0] = di * p0;
        hs2[node * OUT_DIM + 1] = di * p1;
    }
}

// ---------------- agg2: wave/node CSR gather d=2 + fused epilogue ----------------
__global__ __launch_bounds__(256) void agg2_kernel(const int* __restrict__ rowptr,
                                                   const int* __restrict__ cnt,
                                                   const int* __restrict__ csr_src,
                                                   const float* __restrict__ hs2,
                                                   const float* __restrict__ dinv,
                                                   const float* __restrict__ b2,
                                                   float* __restrict__ out, int n) {
    int node = blockIdx.x * 4 + (threadIdx.x >> 6);
    if (node >= n) return;
    int lane = threadIdx.x & 63;
    int start = rowptr[node];
    int deg = cnt[node];

    float a0 = 0.0f, a1 = 0.0f;
    for (int j = lane; j < deg; j += 64) {
        int s = csr_src[start + j];
        float2 v = *(const float2*)&hs2[s * OUT_DIM];
        a0 += v.x;
        a1 += v.y;
    }
#pragma unroll
    for (int off = 32; off > 0; off >>= 1) {
        a0 += __shfl_xor(a0, off);
        a1 += __shfl_xor(a1, off);
    }
    if (lane == 0) {
        float di = dinv[node];
        float2 self = *(const float2*)&hs2[node * OUT_DIM];
        out[node * OUT_DIM + 0] = di * (a0 + self.x) + b2[0];
        out[node * OUT_DIM + 1] = di * (a1 + self.y) + b2[1];
    }
}

extern "C" void kernel_launch(void* const* d_in, const int* in_sizes, int n_in,
                              void* d_out, int out_size, void* d_ws, size_t ws_size,
                              hipStream_t stream) {
    const float* x  = (const float*)d_in[0];
    const int*   ei = (const int*)d_in[1];     // [2][E], row 0 = src, row 1 = dst
    const float* W1 = (const float*)d_in[2];
    const float* b1 = (const float*)d_in[3];
    const float* W2 = (const float*)d_in[4];
    const float* b2 = (const float*)d_in[5];
    float* out = (float*)d_out;

    const int n = N_NODES;
    const int E = in_sizes[1] / 2;

    char* ws = (char*)d_ws;
    int*   gCursor = (int*)  (ws + 0);            // 1.6 KB
    int*   cnt     = (int*)  (ws + (1u << 20));   // 400 KB
    float* dinv    = (float*)(ws + (2u << 20));   // 400 KB
    int*   rowptr  = (int*)  (ws + (3u << 20));   // 400 KB
    float* hs2     = (float*)(ws + (4u << 20));   // 800 KB
    // part (18.3 MB) and hsb (12.8 MB) alias: part is fully consumed by
    // csr_kernel before gemm1_kernel writes hsb.
    int*   part    = (int*)  (ws + (5u << 20));   // NB*BCAP*4 = 18.3 MB
    unsigned short* hsb = (unsigned short*)(ws + (5u << 20));
    int*   csr_src = (int*)  (ws + (25u << 20));  // NB*BCAP*4 = 18.3 MB

    hipMemsetAsync(gCursor, 0, NB * sizeof(int), stream);

    part_kernel<<<(E + CHUNK - 1) / CHUNK, 512, 0, stream>>>(ei, gCursor, part, E);
    csr_kernel<<<NB, 1024, 0, stream>>>(part, gCursor, cnt, dinv, rowptr, csr_src, n);

    gemm1_kernel<<<(n + 63) / 64, 256, 0, stream>>>(x, W1, dinv, hsb, n);
    agg1_kernel<<<(n + 3) / 4, 256, 0, stream>>>(rowptr, cnt, csr_src, hsb, dinv, b1, W2, hs2, n);
    agg2_kernel<<<(n + 3) / 4, 256, 0, stream>>>(rowptr, cnt, csr_src, hs2, dinv, b2, out, n);
}

// Round 10
// 241.081 us; speedup vs baseline: 7.2549x; 1.0365x over previous
//
#include <hip/hip_runtime.h>
#include <hip/hip_bf16.h>

// GCN 2-layer surrogate. Fixed-capacity bucketed counting-sort CSR +
// wave-per-node gather-reduce.
//   bucket = dst >> 8 (391 buckets x 256 nodes), fixed capacity BCAP/bucket
//   part:  bin edges by bucket (int4 loads), claim runs from zeroed gCursor,
//          emit packed int: src | (dst&255)<<20 into bucket region b*BCAP
//   csr:   per bucket (1024 thr): edges held in REGISTERS, per-wave histograms
//          -> cnt/dinv/rowptr, per-wave scatter bases -> csr_src
//   gemm1: MFMA bf16: hs_bf16 = bf16( dinv[r] * (x @ W1) )   (12.8 MB table)
//   agg1:  wave per node; 8 edge-groups x 8 dims/lane, FOUR uint4 row gathers
//          in flight + index prefetch; float4 (pk-f32) accumulation; fused
//          relu + (64->2) + pre-scale epilogue
//   agg2:  2 nodes per wave (32 lanes each), lane-parallel edges on d=2 table

#define N_NODES 100000
#define IN_DIM 128
#define HID_DIM 64
#define OUT_DIM 2
#define NB 391          // ceil(100000/256)
#define BCAP 12288      // slots per bucket (mean 8184, sigma ~90 -> 45 sigma)
#define CROUNDS 12      // BCAP / 1024
#define CHUNK 8192

typedef short bf16x8 __attribute__((ext_vector_type(8)));
typedef float f32x4 __attribute__((ext_vector_type(4)));

__device__ __forceinline__ unsigned short f2bf(float x) {
    unsigned int u = __float_as_uint(x);
    unsigned int r = (u + 0x7FFFu + ((u >> 16) & 1u)) >> 16;   // RNE
    return (unsigned short)r;
}
__device__ __forceinline__ float bflo(unsigned int u) { return __uint_as_float(u << 16); }
__device__ __forceinline__ float bfhi(unsigned int u) { return __uint_as_float(u & 0xFFFF0000u); }
__device__ __forceinline__ float4 unplo(uint4 r) {
    return make_float4(bflo(r.x), bflo(r.y), bflo(r.z), bflo(r.w));
}
__device__ __forceinline__ float4 unphi(uint4 r) {
    return make_float4(bfhi(r.x), bfhi(r.y), bfhi(r.z), bfhi(r.w));
}
__device__ __forceinline__ float4 f4add(float4 a, float4 v) {
    return make_float4(a.x + v.x, a.y + v.y, a.z + v.z, a.w + v.w);
}
__device__ __forceinline__ float4 f4fma(float m, float4 v, float4 a) {
    return make_float4(fmaf(m, v.x, a.x), fmaf(m, v.y, a.y),
                       fmaf(m, v.z, a.z), fmaf(m, v.w, a.w));
}
__device__ __forceinline__ int wave_incl_scan(int v, int laneid) {
#pragma unroll
    for (int off = 1; off < 64; off <<= 1) {
        int u = __shfl_up(v, off);
        if (laneid >= off) v += u;
    }
    return v;
}

// ---------------- part: partition edges into fixed-capacity bucket regions ----------------
__global__ __launch_bounds__(512) void part_kernel(const int* __restrict__ ei,
                                                   int* __restrict__ gCursor,
                                                   int* __restrict__ part, int E) {
    __shared__ int hist[512], lrow[512], gbase[512], lcur[512];
    __shared__ int lpk[CHUNK];
    __shared__ short lbkt[CHUNK];
    __shared__ int wsum[8], wofs[8];
    const int t = threadIdx.x;
    const int lane = t & 63, wv = t >> 6;
    const int base = blockIdx.x * CHUNK;
    const int cntC = min(CHUNK, E - base);

    hist[t] = 0;
    __syncthreads();

    int s[16], d[16];
    bool val[16];
    if (base + CHUNK <= E) {
#pragma unroll
        for (int i = 0; i < 4; ++i) {
            int4 sv = ((const int4*)(ei + base))[t + i * 512];
            int4 dv = ((const int4*)(ei + E + base))[t + i * 512];
            s[i * 4 + 0] = sv.x; s[i * 4 + 1] = sv.y; s[i * 4 + 2] = sv.z; s[i * 4 + 3] = sv.w;
            d[i * 4 + 0] = dv.x; d[i * 4 + 1] = dv.y; d[i * 4 + 2] = dv.z; d[i * 4 + 3] = dv.w;
            val[i * 4 + 0] = val[i * 4 + 1] = val[i * 4 + 2] = val[i * 4 + 3] = true;
        }
    } else {
#pragma unroll
        for (int i = 0; i < 16; ++i) {
            int e = base + t + i * 512;
            val[i] = (e < E);
            if (val[i]) {
                s[i] = ei[e];
                d[i] = ei[E + e];
            }
        }
    }
#pragma unroll
    for (int i = 0; i < 16; ++i)
        if (val[i]) atomicAdd(&hist[d[i] >> 8], 1);
    __syncthreads();

    int v = hist[t];
    int inc = wave_incl_scan(v, lane);
    if (lane == 63) wsum[wv] = inc;
    __syncthreads();
    if (t < 64) {
        int w = (t < 8) ? wsum[t] : 0;
        int wi = wave_incl_scan(w, t);
        if (t < 8) wofs[t] = wi - w;
    }
    __syncthreads();
    int excl = inc - v + wofs[wv];
    if (t < NB && v > 0) {
        int old = atomicAdd(&gCursor[t], v);
        gbase[t] = t * BCAP + old;
    }
    lcur[t] = excl;
    lrow[t] = excl;                    // exclusive offsets for write-out
    __syncthreads();

#pragma unroll
    for (int i = 0; i < 16; ++i) {
        if (val[i]) {
            int b = d[i] >> 8;
            int pos = atomicAdd(&lcur[b], 1);
            lpk[pos] = s[i] | ((d[i] & 255) << 20);
            lbkt[pos] = (short)b;
        }
    }
    __syncthreads();

    for (int i = t; i < cntC; i += 512) {
        int b = lbkt[i];
        int g = gbase[b] + (i - lrow[b]);
        if (g < (b + 1) * BCAP)        // overflow guard (never in practice)
            part[g] = lpk[i];
    }
}

// ---------------- csr: per-bucket CSR finalize (cnt/dinv/rowptr + src sort) ----------------
// Edges live in registers between the two passes; per-wave hist/bases keep
// LDS atomics wave-private.
__global__ __launch_bounds__(1024) void csr_kernel(const int* __restrict__ part,
                                                   const int* __restrict__ gCursor,
                                                   int* __restrict__ cnt,
                                                   float* __restrict__ dinv,
                                                   int* __restrict__ rowptr,
                                                   int* __restrict__ csr_src, int n) {
    __shared__ int wcnt[16][256];      // 16 KB: per-wave hist, then per-wave bases
    __shared__ int wsum[4], wofs[4];
    const int b = blockIdx.x, t = threadIdx.x;
    const int lane = t & 63, wv = t >> 6;
    const int start = b * BCAP;
    const int count = min(gCursor[b], BCAP);

    for (int i = t; i < 16 * 256; i += 1024) ((int*)wcnt)[i] = 0;
    __syncthreads();

    int pk[CROUNDS];
    bool val[CROUNDS];
#pragma unroll
    for (int k = 0; k < CROUNDS; ++k) {
        int i = t + k * 1024;
        val[k] = (i < count);
        pk[k] = val[k] ? part[start + i] : 0;
        if (val[k]) atomicAdd(&wcnt[wv][(pk[k] >> 20) & 255], 1);
    }
    __syncthreads();

    int v = 0;
    if (t < 256) {
        int sum = 0;
#pragma unroll
        for (int w = 0; w < 16; ++w) sum += wcnt[w][t];
        v = sum;
    }
    int inc = 0;
    if (t < 256) {
        inc = wave_incl_scan(v, lane);
        if (lane == 63) wsum[wv] = inc;
    }
    __syncthreads();
    if (t < 64) {
        int w = (t < 4) ? wsum[t] : 0;
        int wi = wave_incl_scan(w, t);
        if (t < 4) wofs[t] = wi - w;
    }
    __syncthreads();
    if (t < 256) {
        int excl = inc - v + wofs[wv];
        int node = (b << 8) + t;
        if (node < n) {
            cnt[node] = v;
            dinv[node] = rsqrtf((float)v + 1.0f);
            rowptr[node] = start + excl;
        }
        int run = excl;                // per-wave scatter bases, in place
#pragma unroll
        for (int w = 0; w < 16; ++w) {
            int c = wcnt[w][t];
            wcnt[w][t] = run;
            run += c;
        }
    }
    __syncthreads();

#pragma unroll
    for (int k = 0; k < CROUNDS; ++k) {
        if (val[k]) {
            int pos = atomicAdd(&wcnt[wv][(pk[k] >> 20) & 255], 1);
            csr_src[start + pos] = pk[k] & 0xFFFFF;
        }
    }
}

// ---------------- GEMM1 (MFMA bf16): hs_bf16 = bf16(dinv[r] * (x @ W1)) ----------------
__global__ __launch_bounds__(256) void gemm1_kernel(const float* __restrict__ x,
                                                    const float* __restrict__ W1,
                                                    const float* __restrict__ dinv,
                                                    unsigned short* __restrict__ hsb, int n) {
    __shared__ unsigned short sX[64 * 136];   // 17.4 KB
    __shared__ unsigned short sW[64 * 136];   // 17.4 KB (transposed W1)
    const int tid = threadIdx.x;
    const int rbase = blockIdx.x * 64;

    // stage W1^T: read [k][c] coalesced as float4, scatter bf16 to [c][k]
    for (int i = tid; i < 2048; i += 256) {
        int k = i >> 4, cq = (i & 15) << 2;
        float4 v = ((const float4*)W1)[i];
        sW[(cq + 0) * 136 + k] = f2bf(v.x);
        sW[(cq + 1) * 136 + k] = f2bf(v.y);
        sW[(cq + 2) * 136 + k] = f2bf(v.z);
        sW[(cq + 3) * 136 + k] = f2bf(v.w);
    }
    // stage x rows as bf16 (row-major, pad 136)
    for (int i = tid; i < 2048; i += 256) {
        int r = i >> 5, kq = (i & 31) << 2;
        int gr = rbase + r;
        float4 v = make_float4(0.f, 0.f, 0.f, 0.f);
        if (gr < n) v = ((const float4*)x)[gr * 32 + (i & 31)];
        ushort4 u;
        u.x = f2bf(v.x); u.y = f2bf(v.y); u.z = f2bf(v.z); u.w = f2bf(v.w);
        *(ushort4*)&sX[r * 136 + kq] = u;
    }
    __syncthreads();

    const int wave = tid >> 6, lane = tid & 63;
    const int quad = lane >> 4, l16 = lane & 15;
    const int rowoff = wave * 16;

    f32x4 acc[4];
#pragma unroll
    for (int t = 0; t < 4; ++t) acc[t] = (f32x4){0.f, 0.f, 0.f, 0.f};

#pragma unroll
    for (int k0 = 0; k0 < 128; k0 += 32) {
        bf16x8 a = *(const bf16x8*)&sX[(rowoff + l16) * 136 + k0 + quad * 8];
#pragma unroll
        for (int t = 0; t < 4; ++t) {
            bf16x8 b = *(const bf16x8*)&sW[(t * 16 + l16) * 136 + k0 + quad * 8];
            acc[t] = __builtin_amdgcn_mfma_f32_16x16x32_bf16(a, b, acc[t], 0, 0, 0);
        }
    }

    // D layout: col = l16, row = quad*4 + reg
#pragma unroll
    for (int r = 0; r < 4; ++r) {
        int grow = rbase + rowoff + quad * 4 + r;
        if (grow < n) {
            float di = dinv[grow];
#pragma unroll
            for (int t = 0; t < 4; ++t)
                hsb[grow * HID_DIM + t * 16 + l16] = f2bf(acc[t][r] * di);
        }
    }
}

// ---------------- agg1: wave/node, 4 uint4 gathers in flight, pk-f32 acc ----------------
// lane = g*8 + l: group g handles edges j = g, g+8, ...; lane loads 16B = dims l*8..l*8+7.
__global__ __launch_bounds__(256) void agg1_kernel(const int* __restrict__ rowptr,
                                                   const int* __restrict__ cnt,
                                                   const int* __restrict__ csr_src,
                                                   const unsigned short* __restrict__ hsb,
                                                   const float* __restrict__ dinv,
                                                   const float* __restrict__ b1,
                                                   const float* __restrict__ W2,
                                                   float* __restrict__ hs2, int n) {
    int node = blockIdx.x * 4 + (threadIdx.x >> 6);
    if (node >= n) return;
    int lane = threadIdx.x & 63;
    int g = lane >> 3;        // edge group 0..7
    int l = lane & 7;         // dim octet 0..7
    int start = rowptr[node];
    int deg = cnt[node];

    float4 alo = make_float4(0.f, 0.f, 0.f, 0.f);   // dims l*8 + {0,2,4,6}
    float4 ahi = make_float4(0.f, 0.f, 0.f, 0.f);   // dims l*8 + {1,3,5,7}
    int s0 = (g      < deg) ? csr_src[start + g]      : 0;
    int s1 = (g +  8 < deg) ? csr_src[start + g +  8] : 0;
    int s2 = (g + 16 < deg) ? csr_src[start + g + 16] : 0;
    int s3 = (g + 24 < deg) ? csr_src[start + g + 24] : 0;
    for (int j = g; j < deg; j += 32) {
        int p0 = (j + 32 < deg) ? csr_src[start + j + 32] : 0;
        int p1 = (j + 40 < deg) ? csr_src[start + j + 40] : 0;
        int p2 = (j + 48 < deg) ? csr_src[start + j + 48] : 0;
        int p3 = (j + 56 < deg) ? csr_src[start + j + 56] : 0;
        uint4 r0 = *(const uint4*)&hsb[(unsigned)s0 * HID_DIM + l * 8];
        uint4 r1 = *(const uint4*)&hsb[(unsigned)s1 * HID_DIM + l * 8];
        uint4 r2 = *(const uint4*)&hsb[(unsigned)s2 * HID_DIM + l * 8];
        uint4 r3 = *(const uint4*)&hsb[(unsigned)s3 * HID_DIM + l * 8];
        float m1 = (j +  8 < deg) ? 1.0f : 0.0f;
        float m2 = (j + 16 < deg) ? 1.0f : 0.0f;
        float m3 = (j + 24 < deg) ? 1.0f : 0.0f;
        alo = f4add(alo, unplo(r0));      ahi = f4add(ahi, unphi(r0));
        alo = f4fma(m1, unplo(r1), alo);  ahi = f4fma(m1, unphi(r1), ahi);
        alo = f4fma(m2, unplo(r2), alo);  ahi = f4fma(m2, unphi(r2), ahi);
        alo = f4fma(m3, unplo(r3), alo);  ahi = f4fma(m3, unphi(r3), ahi);
        s0 = p0; s1 = p1; s2 = p2; s3 = p3;
    }

    float a[8];
    a[0] = alo.x; a[1] = ahi.x; a[2] = alo.y; a[3] = ahi.y;
    a[4] = alo.z; a[5] = ahi.z; a[6] = alo.w; a[7] = ahi.w;

    // combine the 8 edge-groups (dim octets identical across groups)
#pragma unroll
    for (int off = 8; off <= 32; off <<= 1) {
#pragma unroll
        for (int i = 0; i < 8; ++i) a[i] += __shfl_xor(a[i], off);
    }

    // self-loop term
    {
        uint4 raw = *(const uint4*)&hsb[(unsigned)node * HID_DIM + l * 8];
        a[0] += bflo(raw.x); a[1] += bfhi(raw.x);
        a[2] += bflo(raw.y); a[3] += bfhi(raw.y);
        a[4] += bflo(raw.z); a[5] += bfhi(raw.z);
        a[6] += bflo(raw.w); a[7] += bfhi(raw.w);
    }

    float di = dinv[node];
    float4 bb0 = *(const float4*)&b1[l * 8];
    float4 bb1 = *(const float4*)&b1[l * 8 + 4];
    float t0 = fmaxf(fmaf(di, a[0], bb0.x), 0.0f);
    float t1 = fmaxf(fmaf(di, a[1], bb0.y), 0.0f);
    float t2 = fmaxf(fmaf(di, a[2], bb0.z), 0.0f);
    float t3 = fmaxf(fmaf(di, a[3], bb0.w), 0.0f);
    float t4 = fmaxf(fmaf(di, a[4], bb1.x), 0.0f);
    float t5 = fmaxf(fmaf(di, a[5], bb1.y), 0.0f);
    float t6 = fmaxf(fmaf(di, a[6], bb1.z), 0.0f);
    float t7 = fmaxf(fmaf(di, a[7], bb1.w), 0.0f);

    // W2 rows for dims l*8..l*8+7: [d][2] row-major -> 4 float4
    float4 w0 = *(const float4*)&W2[l * 16];
    float4 w1 = *(const float4*)&W2[l * 16 + 4];
    float4 w2 = *(const float4*)&W2[l * 16 + 8];
    float4 w3 = *(const float4*)&W2[l * 16 + 12];
    float p0 = t0 * w0.x + t1 * w0.z + t2 * w1.x + t3 * w1.z
             + t4 * w2.x + t5 * w2.z + t6 * w3.x + t7 * w3.z;
    float p1 = t0 * w0.y + t1 * w0.w + t2 * w1.y + t3 * w1.w
             + t4 * w2.y + t5 * w2.w + t6 * w3.y + t7 * w3.w;
    // reduce over the 8 dim-octets
    p0 += __shfl_xor(p0, 1);  p1 += __shfl_xor(p1, 1);
    p0 += __shfl_xor(p0, 2);  p1 += __shfl_xor(p1, 2);
    p0 += __shfl_xor(p0, 4);  p1 += __shfl_xor(p1, 4);

    if (lane == 0) {
        hs2[node * OUT_DIM + 0] = di * p0;
        hs2[node * OUT_DIM + 1] = di * p1;
    }
}

// ---------------- agg2: 2 nodes/wave CSR gather d=2 + fused epilogue ----------------
__global__ __launch_bounds__(256) void agg2_kernel(const int* __restrict__ rowptr,
                                                   const int* __restrict__ cnt,
                                                   const int* __restrict__ csr_src,
                                                   const float* __restrict__ hs2,
                                                   const float* __restrict__ dinv,
                                                   const float* __restrict__ b2,
                                                   float* __restrict__ out, int n) {
    int node = blockIdx.x * 8 + (threadIdx.x >> 5);
    if (node >= n) return;
    int lane = threadIdx.x & 31;
    int start = rowptr[node];
    int deg = cnt[node];

    float a0 = 0.0f, a1 = 0.0f;
    for (int j = lane; j < deg; j += 32) {
        int s = csr_src[start + j];
        float2 v = *(const float2*)&hs2[s * OUT_DIM];
        a0 += v.x;
        a1 += v.y;
    }
#pragma unroll
    for (int off = 16; off > 0; off >>= 1) {      // xor <=16 stays within 32-group
        a0 += __shfl_xor(a0, off);
        a1 += __shfl_xor(a1, off);
    }
    if (lane == 0) {
        float di = dinv[node];
        float2 self = *(const float2*)&hs2[node * OUT_DIM];
        out[node * OUT_DIM + 0] = di * (a0 + self.x) + b2[0];
        out[node * OUT_DIM + 1] = di * (a1 + self.y) + b2[1];
    }
}

extern "C" void kernel_launch(void* const* d_in, const int* in_sizes, int n_in,
                              void* d_out, int out_size, void* d_ws, size_t ws_size,
                              hipStream_t stream) {
    const float* x  = (const float*)d_in[0];
    const int*   ei = (const int*)d_in[1];     // [2][E], row 0 = src, row 1 = dst
    const float* W1 = (const float*)d_in[2];
    const float* b1 = (const float*)d_in[3];
    const float* W2 = (const float*)d_in[4];
    const float* b2 = (const float*)d_in[5];
    float* out = (float*)d_out;

    const int n = N_NODES;
    const int E = in_sizes[1] / 2;

    char* ws = (char*)d_ws;
    int*   gCursor = (int*)  (ws + 0);            // 1.6 KB
    int*   cnt     = (int*)  (ws + (1u << 20));   // 400 KB
    float* dinv    = (float*)(ws + (2u << 20));   // 400 KB
    int*   rowptr  = (int*)  (ws + (3u << 20));   // 400 KB
    float* hs2     = (float*)(ws + (4u << 20));   // 800 KB
    // part (18.3 MB) and hsb (12.8 MB) alias: part is fully consumed by
    // csr_kernel before gemm1_kernel writes hsb.
    int*   part    = (int*)  (ws + (5u << 20));   // NB*BCAP*4 = 18.3 MB
    unsigned short* hsb = (unsigned short*)(ws + (5u << 20));
    int*   csr_src = (int*)  (ws + (25u << 20));  // NB*BCAP*4 = 18.3 MB

    hipMemsetAsync(gCursor, 0, NB * sizeof(int), stream);

    part_kernel<<<(E + CHUNK - 1) / CHUNK, 512, 0, stream>>>(ei, gCursor, part, E);
    csr_kernel<<<NB, 1024, 0, stream>>>(part, gCursor, cnt, dinv, rowptr, csr_src, n);

    gemm1_kernel<<<(n + 63) / 64, 256, 0, stream>>>(x, W1, dinv, hsb, n);
    agg1_kernel<<<(n + 3) / 4, 256, 0, stream>>>(rowptr, cnt, csr_src, hsb, dinv, b1, W2, hs2, n);
    agg2_kernel<<<(n + 7) / 8, 256, 0, stream>>>(rowptr, cnt, csr_src, hs2, dinv, b2, out, n);
}